// Round 1
// 864.447 us; speedup vs baseline: 1.1900x; 1.1900x over previous
//
#include <hip/hip_runtime.h>

#define NSEQ 20000
#define TT 20
#define FD 128
#define EDG 640000
#define ETOT (EDG + NSEQ)

typedef short bf16x8 __attribute__((ext_vector_type(8)));
typedef float f32x4 __attribute__((ext_vector_type(4)));
typedef unsigned short u16;
typedef unsigned int u32;

__device__ __forceinline__ float bf2f(u16 h) {
  union { u32 u; float f; } v; v.u = ((u32)h) << 16; return v.f;
}
__device__ __forceinline__ u16 f2bf(float f) {
  union { float f; u32 u; } v; v.f = f;
  u32 u = v.u;
  return (u16)((u + 0x7fffu + ((u >> 16) & 1u)) >> 16);
}
// v_rcp_f32: ~1ulp approx reciprocal, 1 instr instead of full-precision div (~9 instr)
__device__ __forceinline__ float fast_rcp(float x) {
  float r; asm("v_rcp_f32 %0, %1" : "=v"(r) : "v"(x)); return r;
}
// packed fp32->bf16 (RNE), 2 elems/instr; same rounding as f2bf
__device__ __forceinline__ u32 cvtpk_bf16(float a, float b) {
  u32 r; asm("v_cvt_pk_bf16_f32 %0, %1, %2" : "=v"(r) : "v"(a), "v"(b)); return r;
}
__device__ __forceinline__ float sigm(float x) { return fast_rcp(1.0f + __expf(-x)); }
__device__ __forceinline__ float tanh_f(float x) { return 1.0f - 2.0f * fast_rcp(__expf(2.0f * x) + 1.0f); }
__device__ __forceinline__ int clampi(int v, int lo, int hi) {
  return v < lo ? lo : (v > hi ? hi : v);
}

// generic loaders over raw input (BF=1: bf16, BF=0: fp32)
template<int BF>
__device__ __forceinline__ bf16x8 ld8(const void* p, size_t i) {
  if (BF) return *(const bf16x8*)((const u16*)p + i);
  f32x4 a = *(const f32x4*)((const float*)p + i);
  f32x4 b = *(const f32x4*)((const float*)p + i + 4);
  union { u32 w[4]; bf16x8 v; } u;
  u.w[0] = cvtpk_bf16(a[0], a[1]);
  u.w[1] = cvtpk_bf16(a[2], a[3]);
  u.w[2] = cvtpk_bf16(b[0], b[1]);
  u.w[3] = cvtpk_bf16(b[2], b[3]);
  return u.v;
}

// canonical-weights element offsets (u16 units) inside the canon block
#define OFF_WIHF 0
#define OFF_WHHF 65536
#define OFF_BF   131072
#define OFF_WIHB 131584
#define OFF_WHHB 197120
#define OFF_BB   262656
#define OFF_W1   263168
#define OFF_W2   394240
#define OFF_A1S  459776
#define OFF_A1D  460288
#define OFF_B1   460800
#define OFF_A2S  461312
#define OFF_A2D  461440
#define OFF_B2   461568
#define OFF_WFC  461696
#define OFF_BFC  462976

// parallel dtype detector: low16 of fp32 words have random exponent fields
__global__ void k_detect(const u32* __restrict__ xw, int* __restrict__ flag) {
  const int lane = threadIdx.x & 63;
  u16 lo = (u16)(xw[lane] & 0xffffu);
  int e = (lo >> 7) & 0xff;
  unsigned long long m = __ballot(e >= 100 && e <= 140);
  if (threadIdx.x == 0) flag[0] = (__popcll(m) >= 32) ? 1 : 0;
}

struct CvtArgs {
  const void* src[16];
  int off[16];
  int cnt[16];
};

template<int BF>
__global__ void k_cvt(CvtArgs a, u16* __restrict__ canon, const int* __restrict__ flag) {
  if (flag[0] != BF) return;
  int idx = blockIdx.x * 256 + threadIdx.x;
  int stride = gridDim.x * 256;
#pragma unroll 1
  for (int s = 0; s < 16; ++s) {
    const void* sp = a.src[s];
    int n = a.cnt[s], off = a.off[s];
    for (int i = idx; i < n; i += stride) {
      canon[off + i] = BF ? ((const u16*)sp)[i] : f2bf(((const float*)sp)[i]);
    }
  }
}

__global__ void k_fill0(u16* __restrict__ out, int n) {
  int i = blockIdx.x * 256 + threadIdx.x;
  if (i < n) out[i] = 0;
}

// ---------------------------------------------------------------------------
// Fused BiLSTM. Blocks take 64 length-sorted seqs; LONGEST blocks dispatch
// FIRST (LPT packing: short blocks fill the tail). One barrier per step via
// double-buffered Ax/Ah; x(t+1) prefetch issued before the MFMA m-loop.
// ---------------------------------------------------------------------------
template<int BF>
__global__ __launch_bounds__(512, 2) void k_lstm(
    const void* __restrict__ x, const int* __restrict__ lengths,
    const int* __restrict__ lperm,
    const u16* __restrict__ canon, u16* __restrict__ hcat,
    const int* __restrict__ flag)
{
  if (flag[0] != BF) return;
  __shared__ u16 Ax[2][64 * 128];
  __shared__ u16 Ah[2][64 * 128];
  __shared__ int lenS[64];
  __shared__ int seqS[64];
  __shared__ int sMax;

  const int tid = threadIdx.x;
  const int wv = tid >> 6;
  const int lane = tid & 63;
  const int q = lane >> 4;
  const int cc = lane & 15;
  const int dir = blockIdx.y;
  // longest-first: lperm ascending, so reverse the block order
  const int b0 = (gridDim.x - 1 - blockIdx.x) * 64;

  const u16* Wi = canon + (dir ? OFF_WIHB : OFF_WIHF);
  const u16* Wh = canon + (dir ? OFF_WHHB : OFF_WHHF);
  const u16* bb = canon + (dir ? OFF_BB : OFF_BF);

  // Weight B-fragments: B[k][n], n = lane&15 (gate column), k = q*8+j.
  bf16x8 wih[4][4], whh[4][4];
  float bv[4];
#pragma unroll
  for (int g = 0; g < 4; ++g) {
    int row = g * 128 + wv * 16 + cc;
#pragma unroll
    for (int kt = 0; kt < 4; ++kt) {
      wih[g][kt] = *(const bf16x8*)(Wi + row * 128 + kt * 32 + q * 8);
      whh[g][kt] = *(const bf16x8*)(Wh + row * 128 + kt * 32 + q * 8);
    }
    bv[g] = bf2f(bb[g * 128 + wv * 16 + cc]);
  }

  if (tid < 64) {
    int s = lperm[clampi(b0 + tid, 0, NSEQ - 1)];
    s = clampi(s, 0, NSEQ - 1);
    seqS[tid] = s;
    int L = clampi(lengths[s], 1, TT);
    lenS[tid] = L;
#pragma unroll
    for (int off = 32; off >= 1; off >>= 1) L = max(L, __shfl_xor(L, off, 64));
    if (tid == 0) sMax = L;
  }
  {
    f32x4 zz = {0.f, 0.f, 0.f, 0.f};
    f32x4* p = (f32x4*)Ah[0];
    for (int i = tid; i < 1024; i += 512) p[i] = zz;   // h0 = 0
  }
  __syncthreads();

  const int tmax = sMax;

  int lenp[4];
#pragma unroll
  for (int m = 0; m < 4; ++m) {
    int v = 0;
#pragma unroll
    for (int r = 0; r < 4; ++r) v |= lenS[m * 16 + q * 4 + r] << (8 * r);
    lenp[m] = v;
  }

  const int lrow = tid >> 3;
  const int lj = tid & 7;
  const int sL = seqS[lrow];
  const int lenL = lenS[lrow];
  const size_t xbase = (size_t)sL * (TT * FD);
  const int ax0 = lrow * 128 + ((lj ^ (lrow & 15)) * 8);
  const int ax1 = lrow * 128 + (((lj + 8) ^ (lrow & 15)) * 8);

  // hoisted XOR-swizzle offsets (constant over t):
  // A-fragment read at elem = m*2048 + rofs[kt]
  int rofs[4];
#pragma unroll
  for (int kt = 0; kt < 4; ++kt) rofs[kt] = cc * 128 + (((4 * kt + q) ^ cc) * 8);
  // h-cell write at elem = m*2048 + cofs[r]
  const int hu = wv * 16 + cc;
  int cofs[4];
#pragma unroll
  for (int r = 0; r < 4; ++r)
    cofs[r] = (q * 4 + r) * 128 + (((hu >> 3) ^ (q * 4 + r)) * 8) + (hu & 7);

  {  // stage x(0) into Ax[0]
    int t0 = dir ? (lenL - 1) : 0;
    bf16x8 d0 = ld8<BF>(x, xbase + t0 * FD + lj * 8);
    bf16x8 d1 = ld8<BF>(x, xbase + t0 * FD + (lj + 8) * 8);
    *(bf16x8*)&Ax[0][ax0] = d0;
    *(bf16x8*)&Ax[0][ax1] = d1;
  }
  float c[4][4] = {};
  int cb = 0;
  __syncthreads();

#pragma unroll 1
  for (int t = 0; t < tmax; ++t) {
    const u16* Axr = Ax[cb];
    u16* Axw = Ax[cb ^ 1];
    const u16* Ahr = Ah[cb];
    u16* Ahw = Ah[cb ^ 1];

    // issue x(t+1) prefetch FIRST: its latency hides behind the MFMA m-loop
    bf16x8 d0 = {}, d1 = {};
    const bool more = (t + 1 < tmax);
    if (more) {
      int tn = t + 1;
      int tt2 = dir ? (lenL - 1 - tn) : tn;
      if (tt2 < 0) tt2 = 0;
      d0 = ld8<BF>(x, xbase + tt2 * FD + lj * 8);
      d1 = ld8<BF>(x, xbase + tt2 * FD + (lj + 8) * 8);
    }

#pragma unroll
    for (int m = 0; m < 4; ++m) {
      const int mb = m * 2048;
      f32x4 acc[4];
#pragma unroll
      for (int g = 0; g < 4; ++g) { f32x4 vi = {bv[g], bv[g], bv[g], bv[g]}; acc[g] = vi; }
#pragma unroll
      for (int kt = 0; kt < 4; ++kt) {
        bf16x8 a = *(const bf16x8*)&Axr[mb + rofs[kt]];
#pragma unroll
        for (int g = 0; g < 4; ++g)
          acc[g] = __builtin_amdgcn_mfma_f32_16x16x32_bf16(a, wih[g][kt], acc[g], 0, 0, 0);
      }
#pragma unroll
      for (int kt = 0; kt < 4; ++kt) {
        bf16x8 a = *(const bf16x8*)&Ahr[mb + rofs[kt]];
#pragma unroll
        for (int g = 0; g < 4; ++g)
          acc[g] = __builtin_amdgcn_mfma_f32_16x16x32_bf16(a, whh[g][kt], acc[g], 0, 0, 0);
      }

      // nonlinearity for this mtile; masked rows carry old h into Ahw
      int lp = lenp[m];
      float hf[4];
#pragma unroll
      for (int r = 0; r < 4; ++r) {
        if (t < ((lp >> (8 * r)) & 255)) {
          float iv = acc[0][r], fv = acc[1][r], gv = acc[2][r], ov = acc[3][r];
          float cn = sigm(fv) * c[m][r] + sigm(iv) * tanh_f(gv);
          c[m][r] = cn;
          hf[r] = sigm(ov) * tanh_f(cn);
        } else {
          hf[r] = bf2f(Ahr[mb + cofs[r]]);   // keep old h (exact bf16 roundtrip)
        }
      }
      u32 w01 = cvtpk_bf16(hf[0], hf[1]);
      u32 w23 = cvtpk_bf16(hf[2], hf[3]);
      Ahw[mb + cofs[0]] = (u16)w01;
      Ahw[mb + cofs[1]] = (u16)(w01 >> 16);
      Ahw[mb + cofs[2]] = (u16)w23;
      Ahw[mb + cofs[3]] = (u16)(w23 >> 16);
    }

    // store prefetched x(t+1) into the OTHER Ax buffer (no reader this step)
    if (more) {
      *(bf16x8*)&Axw[ax0] = d0;
      *(bf16x8*)&Axw[ax1] = d1;
    }
    __syncthreads();   // single barrier per step
    cb ^= 1;
  }

  // epilogue: Ah[cb] holds last-valid h; write to hcat[seq, dir*128:+128]
  for (int i = tid; i < 1024; i += 512) {
    int row = i >> 4, ch = i & 15;
    if (b0 + row < NSEQ) {
      int seq = seqS[row];
      bf16x8 v = *(const bf16x8*)&Ah[cb][row * 128 + ((ch ^ (row & 15)) * 8)];
      *(bf16x8*)(hcat + (size_t)seq * 256 + dir * 128 + ch * 8) = v;
    }
  }
}

// ---------------------------------------------------------------------------
// Tiled bf16 GEMM: C[M,Nc] = A[M,K] * W[Nc,K]^T (A, W both ws-canonical bf16)
// ---------------------------------------------------------------------------
__global__ __launch_bounds__(256) void k_gemm(
    const u16* __restrict__ A, const u16* __restrict__ W, u16* __restrict__ C,
    int M, int Nc, int K)
{
  __shared__ u16 As[128 * 64];
  __shared__ u16 Bs[128 * 64];
  const int tid = threadIdx.x;
  const int wv = tid >> 6, lane = tid & 63, q = lane >> 4, cc = lane & 15;
  const int mblk = blockIdx.x * 128, nblk = blockIdx.y * 128;
  const int wm = (wv & 1) * 64, wn = (wv >> 1) * 64;

  f32x4 acc[4][4] = {};

  const int srow = tid >> 1;
  const int sc0 = (tid & 1) * 4;
  int arow_g = mblk + srow; if (arow_g > M - 1) arow_g = M - 1;
  const u16* aptr = A + (size_t)arow_g * K + sc0 * 8;
  const u16* bptr = W + (size_t)(nblk + srow) * K + sc0 * 8;

  for (int k0 = 0; k0 < K; k0 += 64) {
#pragma unroll
    for (int cch = 0; cch < 4; ++cch) {
      bf16x8 av = *(const bf16x8*)(aptr + k0 + cch * 8);
      bf16x8 bvv = *(const bf16x8*)(bptr + k0 + cch * 8);
      int ch = sc0 + cch;
      *(bf16x8*)&As[srow * 64 + ((ch ^ (srow & 7)) * 8)] = av;
      *(bf16x8*)&Bs[srow * 64 + ((ch ^ (srow & 7)) * 8)] = bvv;
    }
    __syncthreads();
#pragma unroll
    for (int kt = 0; kt < 2; ++kt) {
      bf16x8 af[4];
#pragma unroll
      for (int m = 0; m < 4; ++m) {
        int row = wm + m * 16 + cc;
        af[m] = *(const bf16x8*)&As[row * 64 + (((4 * kt + q) ^ (row & 7)) * 8)];
      }
#pragma unroll
      for (int n = 0; n < 4; ++n) {
        int rowb = wn + n * 16 + cc;
        bf16x8 bfr = *(const bf16x8*)&Bs[rowb * 64 + (((4 * kt + q) ^ (rowb & 7)) * 8)];
#pragma unroll
        for (int m = 0; m < 4; ++m)
          acc[m][n] = __builtin_amdgcn_mfma_f32_16x16x32_bf16(af[m], bfr, acc[m][n], 0, 0, 0);
      }
    }
    __syncthreads();
  }

#pragma unroll
  for (int m = 0; m < 4; ++m)
#pragma unroll
    for (int n = 0; n < 4; ++n)
#pragma unroll
      for (int r = 0; r < 4; ++r) {
        int row = mblk + wm + m * 16 + q * 4 + r;
        int col = nblk + wn + n * 16 + cc;
        if (row < M) C[(size_t)row * Nc + col] = f2bf(acc[m][n][r]);
      }
}

__global__ __launch_bounds__(256) void k_al1(
    const u16* __restrict__ xh1, const u16* __restrict__ canon,
    float* __restrict__ als, float* __restrict__ ald)
{
  const int lane = threadIdx.x & 63;
  const int n = blockIdx.x * 4 + (threadIdx.x >> 6);
  const int hd = lane >> 4;
  bf16x8 xv = *(const bf16x8*)(xh1 + (size_t)n * 512 + lane * 8);
  bf16x8 sv = *(const bf16x8*)(canon + OFF_A1S + hd * 128 + (lane & 15) * 8);
  bf16x8 dv = *(const bf16x8*)(canon + OFF_A1D + hd * 128 + (lane & 15) * 8);
  float ps = 0.f, pd = 0.f;
#pragma unroll
  for (int j = 0; j < 8; ++j) {
    float xf = bf2f((u16)xv[j]);
    ps += xf * bf2f((u16)sv[j]);
    pd += xf * bf2f((u16)dv[j]);
  }
#pragma unroll
  for (int off = 8; off >= 1; off >>= 1) {
    ps += __shfl_xor(ps, off, 64);
    pd += __shfl_xor(pd, off, 64);
  }
  if ((lane & 15) == 0) { als[n * 4 + hd] = ps; ald[n * 4 + hd] = pd; }
}

// GAT layer-1 softmax + aggregation: one block per node, one WAVE per head.
// Fast path (deg<=64, ~all nodes): e/alpha computed ONCE lane-parallel, then
// broadcast per-edge via v_readlane into the feature-parallel serial sum.
__global__ __launch_bounds__(256) void k_agg1(
    const u16* __restrict__ xh1, const float* __restrict__ als, const float* __restrict__ ald,
    const int* __restrict__ offs, const int* __restrict__ csr,
    const u16* __restrict__ canon, u16* __restrict__ h1)
{
  const int lane = threadIdx.x & 63;
  const int hd = threadIdx.x >> 6;
  const int n = blockIdx.x;
  int off0 = offs[n], off1 = offs[n + 1];
  off0 = clampi(off0, 0, ETOT);
  off1 = clampi(off1, off0, ETOT);
  const float ad = ald[(size_t)n * 4 + hd];
  const int deg = off1 - off0;
  const u16* xb = xh1 + hd * 128 + lane * 2;

  float o0 = 0.f, o1 = 0.f;
  if (deg <= 64) {
    int s = 0;
    float e = -1e30f;
    if (lane < deg) {
      s = clampi(csr[off0 + lane], 0, NSEQ - 1);
      float t = als[(size_t)s * 4 + hd] + ad;
      e = t > 0.f ? t : 0.2f * t;
    }
    float mx = e;
#pragma unroll
    for (int off = 32; off >= 1; off >>= 1) mx = fmaxf(mx, __shfl_xor(mx, off, 64));
    float ex = (lane < deg) ? __expf(e - mx) : 0.f;
    float sm = ex;
#pragma unroll
    for (int off = 32; off >= 1; off >>= 1) sm += __shfl_xor(sm, off, 64);
    const float a = ex * fast_rcp(sm + 1e-16f);
    const int sofs = s * 512;
    for (int j = 0; j < deg; ++j) {
      int so = __builtin_amdgcn_readlane(sofs, j);
      float aa = __int_as_float(__builtin_amdgcn_readlane(__float_as_int(a), j));
      u32 xv = *(const u32*)(xb + so);
      o0 += aa * bf2f((u16)(xv & 0xffffu));
      o1 += aa * bf2f((u16)(xv >> 16));
    }
  } else {
    float mx = -1e30f;
    for (int k = off0 + lane; k < off1; k += 64) {
      int s = clampi(csr[k], 0, NSEQ - 1);
      float e = als[(size_t)s * 4 + hd] + ad;
      e = e > 0.f ? e : 0.2f * e;
      mx = fmaxf(mx, e);
    }
#pragma unroll
    for (int off = 32; off >= 1; off >>= 1) mx = fmaxf(mx, __shfl_xor(mx, off, 64));
    float sm = 0.f;
    for (int k = off0 + lane; k < off1; k += 64) {
      int s = clampi(csr[k], 0, NSEQ - 1);
      float e = als[(size_t)s * 4 + hd] + ad;
      e = e > 0.f ? e : 0.2f * e;
      sm += __expf(e - mx);
    }
#pragma unroll
    for (int off = 32; off >= 1; off >>= 1) sm += __shfl_xor(sm, off, 64);
    const float rd = fast_rcp(sm + 1e-16f);
    for (int k = off0; k < off1; ++k) {
      int s = clampi(csr[k], 0, NSEQ - 1);
      float e = als[(size_t)s * 4 + hd] + ad;
      e = e > 0.f ? e : 0.2f * e;
      float a = __expf(e - mx) * rd;
      u32 xv = *(const u32*)(xb + (size_t)s * 512);
      o0 += a * bf2f((u16)(xv & 0xffffu));
      o1 += a * bf2f((u16)(xv >> 16));
    }
  }
  o0 += bf2f(canon[OFF_B1 + hd * 128 + lane * 2]);
  o1 += bf2f(canon[OFF_B1 + hd * 128 + lane * 2 + 1]);
  o0 = o0 > 0.f ? o0 : 0.f;
  o1 = o1 > 0.f ? o1 : 0.f;
  u32 pk = (u32)f2bf(o0) | ((u32)f2bf(o1) << 16);
  *(u32*)(h1 + (size_t)n * 512 + hd * 128 + lane * 2) = pk;
}

__global__ __launch_bounds__(256) void k_al2(
    const u16* __restrict__ xh2, const u16* __restrict__ canon,
    float* __restrict__ als2, float* __restrict__ ald2)
{
  const int lane = threadIdx.x & 63;
  const int n = blockIdx.x * 4 + (threadIdx.x >> 6);
  float x0 = bf2f(xh2[(size_t)n * 128 + lane * 2]);
  float x1 = bf2f(xh2[(size_t)n * 128 + lane * 2 + 1]);
  float ps = x0 * bf2f(canon[OFF_A2S + lane * 2]) + x1 * bf2f(canon[OFF_A2S + lane * 2 + 1]);
  float pd = x0 * bf2f(canon[OFF_A2D + lane * 2]) + x1 * bf2f(canon[OFF_A2D + lane * 2 + 1]);
#pragma unroll
  for (int off = 32; off >= 1; off >>= 1) {
    ps += __shfl_xor(ps, off, 64);
    pd += __shfl_xor(pd, off, 64);
  }
  if (lane == 0) { als2[n] = ps; ald2[n] = pd; }
}

__global__ __launch_bounds__(256) void k_agg2(
    const u16* __restrict__ xh2, const float* __restrict__ als2, const float* __restrict__ ald2,
    const int* __restrict__ offs, const int* __restrict__ csr,
    const u16* __restrict__ canon, float* __restrict__ h2)
{
  const int lane = threadIdx.x & 63;
  const int n = blockIdx.x * 4 + (threadIdx.x >> 6);
  int off0 = offs[n], off1 = offs[n + 1];
  off0 = clampi(off0, 0, ETOT);
  off1 = clampi(off1, off0, ETOT);
  const float adn = ald2[n];
  const int deg = off1 - off0;

  float o0 = 0.f, o1 = 0.f;
  if (deg <= 64) {
    int s = 0;
    float e = -1e30f;
    if (lane < deg) {
      s = clampi(csr[off0 + lane], 0, NSEQ - 1);
      float t = als2[s] + adn;
      e = t > 0.f ? t : 0.2f * t;
    }
    float mx = e;
#pragma unroll
    for (int off = 32; off >= 1; off >>= 1) mx = fmaxf(mx, __shfl_xor(mx, off, 64));
    float ex = (lane < deg) ? __expf(e - mx) : 0.f;
    float sm = ex;
#pragma unroll
    for (int off = 32; off >= 1; off >>= 1) sm += __shfl_xor(sm, off, 64);
    const float a = ex * fast_rcp(sm + 1e-16f);
    const int sofs = s * 128;
    for (int j = 0; j < deg; ++j) {
      int so = __builtin_amdgcn_readlane(sofs, j);
      float aa = __int_as_float(__builtin_amdgcn_readlane(__float_as_int(a), j));
      u32 xv = *(const u32*)(xh2 + so + lane * 2);
      o0 += aa * bf2f((u16)(xv & 0xffffu));
      o1 += aa * bf2f((u16)(xv >> 16));
    }
  } else {
    float mx = -1e30f;
    for (int k = off0 + lane; k < off1; k += 64) {
      float e = als2[clampi(csr[k], 0, NSEQ - 1)] + adn;
      e = e > 0.f ? e : 0.2f * e;
      mx = fmaxf(mx, e);
    }
#pragma unroll
    for (int off = 32; off >= 1; off >>= 1) mx = fmaxf(mx, __shfl_xor(mx, off, 64));
    float sm = 0.f;
    for (int k = off0 + lane; k < off1; k += 64) {
      float e = als2[clampi(csr[k], 0, NSEQ - 1)] + adn;
      e = e > 0.f ? e : 0.2f * e;
      sm += __expf(e - mx);
    }
#pragma unroll
    for (int off = 32; off >= 1; off >>= 1) sm += __shfl_xor(sm, off, 64);
    float rd = fast_rcp(sm + 1e-16f);
    for (int k = off0; k < off1; ++k) {
      int s = clampi(csr[k], 0, NSEQ - 1);
      float e = als2[s] + adn;
      e = e > 0.f ? e : 0.2f * e;
      float a = __expf(e - mx) * rd;
      u32 xv = *(const u32*)(xh2 + (size_t)s * 128 + lane * 2);
      o0 += a * bf2f((u16)(xv & 0xffffu));
      o1 += a * bf2f((u16)(xv >> 16));
    }
  }
  o0 += bf2f(canon[OFF_B2 + lane * 2]);     o0 = o0 > 0.f ? o0 : 0.f;
  o1 += bf2f(canon[OFF_B2 + lane * 2 + 1]); o1 = o1 > 0.f ? o1 : 0.f;
  float2 st; st.x = o0; st.y = o1;
  *(float2*)(h2 + (size_t)n * 128 + lane * 2) = st;
}

template<int BF>
__global__ __launch_bounds__(256) void k_fc(
    const float* __restrict__ h2, const u16* __restrict__ canon,
    void* __restrict__ out, const int* __restrict__ flag)
{
  if (flag[0] != BF) return;
  const int lane = threadIdx.x & 63;
  const int n = blockIdx.x * 4 + (threadIdx.x >> 6);
  float a0 = h2[(size_t)n * 128 + lane];
  float a1 = h2[(size_t)n * 128 + 64 + lane];
  float res[10];
#pragma unroll
  for (int cls = 0; cls < 10; ++cls) {
    float p = a0 * bf2f(canon[OFF_WFC + cls * 128 + lane]) +
              a1 * bf2f(canon[OFF_WFC + cls * 128 + 64 + lane]);
#pragma unroll
    for (int off = 32; off >= 1; off >>= 1) p += __shfl_xor(p, off, 64);
    float v = p + bf2f(canon[OFF_BFC + cls]);
    res[cls] = (fabsf(v) < 1e30f) ? v : 0.f;
  }
  if (BF) {
    if (lane < 5) {
      u32 pk = (u32)f2bf(res[lane * 2]) | ((u32)f2bf(res[lane * 2 + 1]) << 16);
      ((u32*)out)[(size_t)n * 5 + lane] = pk;
    }
  } else {
    if (lane < 10) ((float*)out)[(size_t)n * 10 + lane] = res[lane];
  }
}

// ---- fused setup: zero, histograms (deg + length), scans, scatters ----
__global__ void k_zero_all(int* __restrict__ deg, int* __restrict__ lcnt) {
  int i = blockIdx.x * 256 + threadIdx.x;
  if (i < NSEQ) deg[i] = 0;
  if (i < 64) lcnt[i] = 0;
}

__global__ void k_hist_all(const int* __restrict__ ei, const int* __restrict__ lengths,
                           int* __restrict__ deg, int* __restrict__ lcnt) {
  int i = blockIdx.x * 256 + threadIdx.x;
  if (i < ETOT) {
    int d = (i < EDG) ? ei[EDG + i] : (i - EDG);
    d = clampi(d, 0, NSEQ - 1);
    atomicAdd(&deg[d], 1);
  }
  if (i < NSEQ) atomicAdd(&lcnt[clampi(lengths[i], 1, TT) - 1], 1);
}

// single-block exclusive scan over deg (+ tiny serial length-scan by thread 0)
__global__ __launch_bounds__(1024) void k_scan(const int* __restrict__ deg,
                                               int* __restrict__ offs, int* __restrict__ cur,
                                               const int* __restrict__ lcnt,
                                               int* __restrict__ lcur) {
  __shared__ int wsum[16];
  const int tid = threadIdx.x;
  if (tid == 0) {
    int run = 0;
    for (int i = 0; i < TT; ++i) { lcur[i] = run; run += lcnt[i]; }
  }
  const int lane = tid & 63, wv = tid >> 6;
  const int CHUNK = 20;
  int base = tid * CHUNK;
  int loc[20];
  int s = 0;
#pragma unroll
  for (int i = 0; i < CHUNK; ++i) {
    int idx = base + i;
    int v = (idx < NSEQ) ? deg[idx] : 0;
    loc[i] = s;
    s += v;
  }
  int inc = s;
#pragma unroll
  for (int off = 1; off < 64; off <<= 1) {
    int t2 = __shfl_up(inc, off, 64);
    if (lane >= off) inc += t2;
  }
  if (lane == 63) wsum[wv] = inc;
  __syncthreads();
  int wbase = 0;
  for (int i = 0; i < wv; ++i) wbase += wsum[i];
  int tbase = wbase + inc - s;
#pragma unroll
  for (int i = 0; i < CHUNK; ++i) {
    int idx = base + i;
    if (idx < NSEQ) {
      int st = tbase + loc[i];
      offs[idx] = st;
      cur[idx] = st;
    }
  }
  if (tid == 0) offs[NSEQ] = ETOT;
}

__global__ void k_scatter_all(const int* __restrict__ ei, const int* __restrict__ lengths,
                              int* __restrict__ cur, int* __restrict__ csr,
                              int* __restrict__ lcur, int* __restrict__ lperm) {
  int i = blockIdx.x * 256 + threadIdx.x;
  if (i < ETOT) {
    int s, d;
    if (i < EDG) { s = ei[i]; d = ei[EDG + i]; }
    else { s = i - EDG; d = s; }
    d = clampi(d, 0, NSEQ - 1);
    int pos = atomicAdd(&cur[d], 1);
    pos = clampi(pos, 0, ETOT - 1);
    csr[pos] = s;
  }
  if (i < NSEQ) {
    int b = clampi(lengths[i], 1, TT) - 1;
    int pos = atomicAdd(&lcur[b], 1);
    lperm[clampi(pos, 0, NSEQ - 1)] = i;
  }
}

extern "C" void kernel_launch(void* const* d_in, const int* in_sizes, int n_in,
                              void* d_out, int out_size, void* d_ws, size_t ws_size,
                              hipStream_t stream) {
  (void)in_sizes; (void)n_in;
  const void* x     = d_in[0];
  const int* lengths= (const int*)d_in[1];
  const int* ei     = (const int*)d_in[2];

  const size_t NEED = 45769344u;
  if (ws_size < NEED) {
    k_fill0<<<(out_size + 255) / 256, 256, 0, stream>>>((u16*)d_out, out_size);
    return;
  }

  char* w = (char*)d_ws;
  size_t o = 0;
  auto alloc = [&](size_t b) { char* p = w + o; o += (b + 255) & ~(size_t)255; return p; };
  int*  flag = (int*)  alloc(256);
  u16*  canon= (u16*)  alloc(1048576);
  int*  deg  = (int*)  alloc((size_t)NSEQ * 4);
  int*  offs = (int*)  alloc((size_t)(NSEQ + 1) * 4);
  int*  cur  = (int*)  alloc((size_t)NSEQ * 4);
  int*  csr  = (int*)  alloc((size_t)ETOT * 4);
  float* als1= (float*)alloc((size_t)NSEQ * 4 * 4);
  float* ald1= (float*)alloc((size_t)NSEQ * 4 * 4);
  char* regB = alloc((size_t)NSEQ * 512 * 2);            // xh1 / later xh2,h2,als2,ald2
  u16*  xh1  = (u16*)regB;
  u16*  xh2  = (u16*)regB;
  float* h2  = (float*)(regB + (size_t)NSEQ * 128 * 2);
  float* als2= (float*)(regB + (size_t)NSEQ * 128 * 2 + (size_t)NSEQ * 128 * 4);
  float* ald2= als2 + NSEQ;
  char* regA = alloc((size_t)NSEQ * 256 * 2);            // hcat / later h1 (w/ ext)
  u16*  hcat = (u16*)regA;
  u16*  h1   = (u16*)regA;
  alloc((size_t)NSEQ * 256 * 2);                         // h1 extension

  // length-sort scratch lives in regB (dead until k_gemm #1)
  int* lperm = (int*)regB;                       // 80000 B
  int* lcnt  = (int*)(regB + 80128);             // 32 ints
  int* lcur  = (int*)(regB + 80256);             // 32 ints

  k_detect<<<1, 64, 0, stream>>>((const u32*)x, flag);
  CvtArgs ca;
  const int srcIdx[16] = {3, 4, 5, 6, 7, 8, 9, 13, 10, 11, 12, 14, 15, 16, 17, 18};
  const int offv[16]   = {OFF_WIHF, OFF_WHHF, OFF_BF, OFF_WIHB, OFF_WHHB, OFF_BB,
                          OFF_W1, OFF_W2, OFF_A1S, OFF_A1D, OFF_B1,
                          OFF_A2S, OFF_A2D, OFF_B2, OFF_WFC, OFF_BFC};
  const int cntv[16]   = {65536, 65536, 512, 65536, 65536, 512,
                          131072, 65536, 512, 512, 512, 128, 128, 128, 1280, 10};
  for (int i = 0; i < 16; ++i) { ca.src[i] = d_in[srcIdx[i]]; ca.off[i] = offv[i]; ca.cnt[i] = cntv[i]; }
  k_cvt<1><<<256, 256, 0, stream>>>(ca, canon, flag);
  k_cvt<0><<<256, 256, 0, stream>>>(ca, canon, flag);

  // fused setup: zero -> hist(deg+len) -> scan(offs/cur + lcur) -> scatter(csr + lperm)
  k_zero_all<<<(NSEQ + 255) / 256, 256, 0, stream>>>(deg, lcnt);
  k_hist_all<<<(ETOT + 255) / 256, 256, 0, stream>>>(ei, lengths, deg, lcnt);
  k_scan<<<1, 1024, 0, stream>>>(deg, offs, cur, lcnt, lcur);
  k_scatter_all<<<(ETOT + 255) / 256, 256, 0, stream>>>(ei, lengths, cur, csr, lcur, lperm);

  k_lstm<1><<<dim3(313, 2), 512, 0, stream>>>(x, lengths, lperm, canon, hcat, flag);
  k_lstm<0><<<dim3(313, 2), 512, 0, stream>>>(x, lengths, lperm, canon, hcat, flag);

  k_gemm<<<dim3(157, 4), 256, 0, stream>>>(hcat, canon + OFF_W1, xh1, NSEQ, 512, 256);
  k_al1<<<5000, 256, 0, stream>>>(xh1, canon, als1, ald1);
  k_agg1<<<NSEQ, 256, 0, stream>>>(xh1, als1, ald1, offs, csr, canon, h1);

  k_gemm<<<dim3(157, 1), 256, 0, stream>>>(h1, canon + OFF_W2, xh2, NSEQ, 128, 512);
  k_al2<<<5000, 256, 0, stream>>>(xh2, canon, als2, ald2);
  k_agg2<<<5000, 256, 0, stream>>>(xh2, als2, ald2, offs, csr, canon, h2);

  k_fc<1><<<5000, 256, 0, stream>>>(h2, canon, d_out, flag);
  k_fc<0><<<5000, 256, 0, stream>>>(h2, canon, d_out, flag);
}

// Round 2
// 822.589 us; speedup vs baseline: 1.2506x; 1.0509x over previous
//
#include <hip/hip_runtime.h>

#define NSEQ 20000
#define TT 20
#define FD 128
#define EDG 640000
#define ETOT (EDG + NSEQ)

typedef short bf16x8 __attribute__((ext_vector_type(8)));
typedef float f32x4 __attribute__((ext_vector_type(4)));
typedef unsigned short u16;
typedef unsigned int u32;

__device__ __forceinline__ float bf2f(u16 h) {
  union { u32 u; float f; } v; v.u = ((u32)h) << 16; return v.f;
}
__device__ __forceinline__ float bf_lo(u32 w) {
  union { u32 u; float f; } v; v.u = w << 16; return v.f;
}
__device__ __forceinline__ float bf_hi(u32 w) {
  union { u32 u; float f; } v; v.u = w & 0xffff0000u; return v.f;
}
__device__ __forceinline__ u16 f2bf(float f) {
  union { float f; u32 u; } v; v.f = f;
  u32 u = v.u;
  return (u16)((u + 0x7fffu + ((u >> 16) & 1u)) >> 16);
}
// v_rcp_f32: ~1ulp approx reciprocal, 1 instr instead of full-precision div (~9 instr)
__device__ __forceinline__ float fast_rcp(float x) {
  float r; asm("v_rcp_f32 %0, %1" : "=v"(r) : "v"(x)); return r;
}
// packed fp32->bf16 (RNE), 2 elems/instr; lo = first arg
__device__ __forceinline__ u32 cvtpk_bf16(float a, float b) {
  u32 r; asm("v_cvt_pk_bf16_f32 %0, %1, %2" : "=v"(r) : "v"(a), "v"(b)); return r;
}
__device__ __forceinline__ float sigm(float x) { return fast_rcp(1.0f + __expf(-x)); }
__device__ __forceinline__ float tanh_f(float x) { return 1.0f - 2.0f * fast_rcp(__expf(2.0f * x) + 1.0f); }
__device__ __forceinline__ int clampi(int v, int lo, int hi) {
  return v < lo ? lo : (v > hi ? hi : v);
}

// generic loaders over raw input (BF=1: bf16, BF=0: fp32)
template<int BF>
__device__ __forceinline__ bf16x8 ld8(const void* p, size_t i) {
  if (BF) return *(const bf16x8*)((const u16*)p + i);
  f32x4 a = *(const f32x4*)((const float*)p + i);
  f32x4 b = *(const f32x4*)((const float*)p + i + 4);
  union { u32 w[4]; bf16x8 v; } u;
  u.w[0] = cvtpk_bf16(a[0], a[1]);
  u.w[1] = cvtpk_bf16(a[2], a[3]);
  u.w[2] = cvtpk_bf16(b[0], b[1]);
  u.w[3] = cvtpk_bf16(b[2], b[3]);
  return u.v;
}

// canonical-weights element offsets (u16 units) inside the canon block
#define OFF_WIHF 0
#define OFF_WHHF 65536
#define OFF_BF   131072
#define OFF_WIHB 131584
#define OFF_WHHB 197120
#define OFF_BB   262656
#define OFF_W1   263168
#define OFF_W2   394240
#define OFF_A1S  459776
#define OFF_A1D  460288
#define OFF_B1   460800
#define OFF_A2S  461312
#define OFF_A2D  461440
#define OFF_B2   461568
#define OFF_WFC  461696
#define OFF_BFC  462976

// parallel dtype detector: low16 of fp32 words have random exponent fields
__global__ void k_detect(const u32* __restrict__ xw, int* __restrict__ flag) {
  const int lane = threadIdx.x & 63;
  u16 lo = (u16)(xw[lane] & 0xffffu);
  int e = (lo >> 7) & 0xff;
  unsigned long long m = __ballot(e >= 100 && e <= 140);
  if (threadIdx.x == 0) flag[0] = (__popcll(m) >= 32) ? 1 : 0;
}

struct CvtArgs {
  const void* src[16];
  int off[16];
  int cnt[16];
};

template<int BF>
__global__ void k_cvt(CvtArgs a, u16* __restrict__ canon, const int* __restrict__ flag) {
  if (flag[0] != BF) return;
  int idx = blockIdx.x * 256 + threadIdx.x;
  int stride = gridDim.x * 256;
#pragma unroll 1
  for (int s = 0; s < 16; ++s) {
    const void* sp = a.src[s];
    int n = a.cnt[s], off = a.off[s];
    for (int i = idx; i < n; i += stride) {
      canon[off + i] = BF ? ((const u16*)sp)[i] : f2bf(((const float*)sp)[i]);
    }
  }
}

__global__ void k_fill0(u16* __restrict__ out, int n) {
  int i = blockIdx.x * 256 + threadIdx.x;
  if (i < n) out[i] = 0;
}

// ---------------------------------------------------------------------------
// Fused BiLSTM. Blocks take 64 length-sorted seqs; LONGEST blocks dispatch
// FIRST. One barrier per step via double-buffered Ax/Ah; x(t+1) prefetch
// issued before the MFMA m-loop. SWAPPED-OPERAND MFMA: D[i=gatecol][j=seq],
// so each lane owns one seq (cc) and 4 consecutive gate cols (q*4+r) ->
// packed b64 h-writeback, per-lane-uniform length mask.
// ---------------------------------------------------------------------------
template<int BF>
__global__ __launch_bounds__(512, 2) void k_lstm(
    const void* __restrict__ x, const int* __restrict__ lengths,
    const int* __restrict__ lperm,
    const u16* __restrict__ canon, u16* __restrict__ hcat,
    const int* __restrict__ flag)
{
  if (flag[0] != BF) return;
  __shared__ u16 Ax[2][64 * 128];
  __shared__ u16 Ah[2][64 * 128];
  __shared__ int lenS[64];
  __shared__ int seqS[64];
  __shared__ int sMax;

  const int tid = threadIdx.x;
  const int wv = tid >> 6;
  const int lane = tid & 63;
  const int q = lane >> 4;
  const int cc = lane & 15;
  const int dir = blockIdx.y;
  const int b0 = (gridDim.x - 1 - blockIdx.x) * 64;

  const u16* Wi = canon + (dir ? OFF_WIHB : OFF_WIHF);
  const u16* Wh = canon + (dir ? OFF_WHHB : OFF_WHHF);
  const u16* bb = canon + (dir ? OFF_BB : OFF_BF);

  // Weight fragments (A-operand now): lane&15 = gate col, k = q*8+j.
  bf16x8 wih[4][4], whh[4][4];
  uint2 bvp[4];  // packed bf16 bias for cols wv*16+q*4 .. +3, per gate
#pragma unroll
  for (int g = 0; g < 4; ++g) {
    int row = g * 128 + wv * 16 + cc;
#pragma unroll
    for (int kt = 0; kt < 4; ++kt) {
      wih[g][kt] = *(const bf16x8*)(Wi + row * 128 + kt * 32 + q * 8);
      whh[g][kt] = *(const bf16x8*)(Wh + row * 128 + kt * 32 + q * 8);
    }
    bvp[g] = *(const uint2*)(bb + g * 128 + wv * 16 + q * 4);
  }

  if (tid < 64) {
    int s = lperm[clampi(b0 + tid, 0, NSEQ - 1)];
    s = clampi(s, 0, NSEQ - 1);
    seqS[tid] = s;
    int L = clampi(lengths[s], 1, TT);
    lenS[tid] = L;
#pragma unroll
    for (int off = 32; off >= 1; off >>= 1) L = max(L, __shfl_xor(L, off, 64));
    if (tid == 0) sMax = L;
  }
  {
    f32x4 zz = {0.f, 0.f, 0.f, 0.f};
    f32x4* p = (f32x4*)Ah[0];
    for (int i = tid; i < 1024; i += 512) p[i] = zz;   // h0 = 0
  }
  __syncthreads();

  const int tmax = sMax;

  // per-lane seq lengths (seq = m*16+cc; uniform over q,r)
  int lenq[4];
#pragma unroll
  for (int m = 0; m < 4; ++m) lenq[m] = lenS[m * 16 + cc];

  const int lrow = tid >> 3;
  const int lj = tid & 7;
  const int sL = seqS[lrow];
  const int lenL = lenS[lrow];
  const size_t xbase = (size_t)sL * (TT * FD);
  const int ax0 = lrow * 128 + ((lj ^ (lrow & 15)) * 8);
  const int ax1 = lrow * 128 + (((lj + 8) ^ (lrow & 15)) * 8);

  // hoisted XOR-swizzle offsets (constant over t):
  // B-fragment (x/h) read at elem = m*2048 + rofs[kt]
  int rofs[4];
#pragma unroll
  for (int kt = 0; kt < 4; ++kt) rofs[kt] = cc * 128 + (((4 * kt + q) ^ cc) * 8);
  // packed h-write (4 cols wv*16+q*4.. of seq m*16+cc): elem = m*2048 + awbase
  const int awbase = cc * 128 + (((wv * 2 + (q >> 1)) ^ cc) * 8) + (q & 1) * 4;

  {  // stage x(0) into Ax[0]
    int t0 = dir ? (lenL - 1) : 0;
    bf16x8 d0 = ld8<BF>(x, xbase + t0 * FD + lj * 8);
    bf16x8 d1 = ld8<BF>(x, xbase + t0 * FD + (lj + 8) * 8);
    *(bf16x8*)&Ax[0][ax0] = d0;
    *(bf16x8*)&Ax[0][ax1] = d1;
  }
  float c[4][4] = {};
  int cb = 0;
  __syncthreads();

#pragma unroll 1
  for (int t = 0; t < tmax; ++t) {
    const u16* Axr = Ax[cb];
    u16* Axw = Ax[cb ^ 1];
    const u16* Ahr = Ah[cb];
    u16* Ahw = Ah[cb ^ 1];

    // issue x(t+1) prefetch FIRST: its latency hides behind the MFMA m-loop
    bf16x8 d0 = {}, d1 = {};
    const bool more = (t + 1 < tmax);
    if (more) {
      int tn = t + 1;
      int tt2 = dir ? (lenL - 1 - tn) : tn;
      if (tt2 < 0) tt2 = 0;
      d0 = ld8<BF>(x, xbase + tt2 * FD + lj * 8);
      d1 = ld8<BF>(x, xbase + tt2 * FD + (lj + 8) * 8);
    }

#pragma unroll
    for (int m = 0; m < 4; ++m) {
      const int mb = m * 2048;
      f32x4 acc[4];
#pragma unroll
      for (int g = 0; g < 4; ++g) {
        f32x4 vi = {bf_lo(bvp[g].x), bf_hi(bvp[g].x), bf_lo(bvp[g].y), bf_hi(bvp[g].y)};
        acc[g] = vi;
      }
#pragma unroll
      for (int kt = 0; kt < 4; ++kt) {
        bf16x8 b = *(const bf16x8*)&Axr[mb + rofs[kt]];
#pragma unroll
        for (int g = 0; g < 4; ++g)
          acc[g] = __builtin_amdgcn_mfma_f32_16x16x32_bf16(wih[g][kt], b, acc[g], 0, 0, 0);
      }
#pragma unroll
      for (int kt = 0; kt < 4; ++kt) {
        bf16x8 b = *(const bf16x8*)&Ahr[mb + rofs[kt]];
#pragma unroll
        for (int g = 0; g < 4; ++g)
          acc[g] = __builtin_amdgcn_mfma_f32_16x16x32_bf16(whh[g][kt], b, acc[g], 0, 0, 0);
      }

      // nonlinearity; lane-uniform mask (seq = m*16+cc); packed b64 writeback
      uint2 hw;
      if (t < lenq[m]) {
        float hf[4];
#pragma unroll
        for (int r = 0; r < 4; ++r) {
          float iv = acc[0][r], fv = acc[1][r], gv = acc[2][r], ov = acc[3][r];
          float cn = sigm(fv) * c[m][r] + sigm(iv) * tanh_f(gv);
          c[m][r] = cn;
          hf[r] = sigm(ov) * tanh_f(cn);
        }
        hw.x = cvtpk_bf16(hf[0], hf[1]);
        hw.y = cvtpk_bf16(hf[2], hf[3]);
      } else {
        hw = *(const uint2*)&Ahr[mb + awbase];   // carry old h
      }
      *(uint2*)&Ahw[mb + awbase] = hw;
    }

    // store prefetched x(t+1) into the OTHER Ax buffer (no reader this step)
    if (more) {
      *(bf16x8*)&Axw[ax0] = d0;
      *(bf16x8*)&Axw[ax1] = d1;
    }
    __syncthreads();   // single barrier per step
    cb ^= 1;
  }

  // epilogue: Ah[cb] holds last-valid h; write to hcat[seq, dir*128:+128]
  for (int i = tid; i < 1024; i += 512) {
    int row = i >> 4, ch = i & 15;
    if (b0 + row < NSEQ) {
      int seq = seqS[row];
      bf16x8 v = *(const bf16x8*)&Ah[cb][row * 128 + ((ch ^ (row & 15)) * 8)];
      *(bf16x8*)(hcat + (size_t)seq * 256 + dir * 128 + ch * 8) = v;
    }
  }
}

// ---------------------------------------------------------------------------
// Tiled bf16 GEMM: C[M,Nc] = A[M,K] * W[Nc,K]^T. Swapped-operand MFMA ->
// lane holds 4 consecutive cols -> dwordx2 C-stores. Fused attention-logit
// epilogue: als[row*stride+by] = sum_col C[row][col]*aS[col] (and aD).
// ---------------------------------------------------------------------------
__global__ __launch_bounds__(256) void k_gemm(
    const u16* __restrict__ A, const u16* __restrict__ W, u16* __restrict__ C,
    int M, int Nc, int K,
    const u16* __restrict__ aS, const u16* __restrict__ aD,
    float* __restrict__ als, float* __restrict__ ald, int alsStride)
{
  __shared__ u16 As[128 * 64];
  __shared__ u16 Bs[128 * 64];
  const int tid = threadIdx.x;
  const int wv = tid >> 6, lane = tid & 63, q = lane >> 4, cc = lane & 15;
  const int mblk = blockIdx.x * 128, nblk = blockIdx.y * 128;
  const int wm = (wv & 1) * 64, wn = (wv >> 1) * 64;

  f32x4 acc[4][4] = {};

  const int srow = tid >> 1;
  const int sc0 = (tid & 1) * 4;
  int arow_g = mblk + srow; if (arow_g > M - 1) arow_g = M - 1;
  const u16* aptr = A + (size_t)arow_g * K + sc0 * 8;
  const u16* bptr = W + (size_t)(nblk + srow) * K + sc0 * 8;

  for (int k0 = 0; k0 < K; k0 += 64) {
#pragma unroll
    for (int cch = 0; cch < 4; ++cch) {
      bf16x8 av = *(const bf16x8*)(aptr + k0 + cch * 8);
      bf16x8 bvv = *(const bf16x8*)(bptr + k0 + cch * 8);
      int ch = sc0 + cch;
      *(bf16x8*)&As[srow * 64 + ((ch ^ (srow & 7)) * 8)] = av;
      *(bf16x8*)&Bs[srow * 64 + ((ch ^ (srow & 7)) * 8)] = bvv;
    }
    __syncthreads();
#pragma unroll
    for (int kt = 0; kt < 2; ++kt) {
      bf16x8 af[4];
#pragma unroll
      for (int m = 0; m < 4; ++m) {
        int row = wm + m * 16 + cc;
        af[m] = *(const bf16x8*)&As[row * 64 + (((4 * kt + q) ^ (row & 7)) * 8)];
      }
#pragma unroll
      for (int n = 0; n < 4; ++n) {
        int rowb = wn + n * 16 + cc;
        bf16x8 bfr = *(const bf16x8*)&Bs[rowb * 64 + (((4 * kt + q) ^ (rowb & 7)) * 8)];
#pragma unroll
        for (int m = 0; m < 4; ++m)
          acc[m][n] = __builtin_amdgcn_mfma_f32_16x16x32_bf16(bfr, af[m], acc[m][n], 0, 0, 0);
      }
    }
    __syncthreads();
  }

  // C-store: lane = (seq row = wm+m*16+cc, cols wn+n*16+q*4..+3) -> dwordx2
  float pls[4] = {}, pld[4] = {};
#pragma unroll
  for (int n = 0; n < 4; ++n) {
    uint2 ws = *(const uint2*)(aS + nblk + wn + n * 16 + q * 4);
    uint2 wd = *(const uint2*)(aD + nblk + wn + n * 16 + q * 4);
    float s0 = bf_lo(ws.x), s1 = bf_hi(ws.x), s2 = bf_lo(ws.y), s3 = bf_hi(ws.y);
    float d0 = bf_lo(wd.x), d1 = bf_hi(wd.x), d2 = bf_lo(wd.y), d3 = bf_hi(wd.y);
#pragma unroll
    for (int m = 0; m < 4; ++m) {
      int row = mblk + wm + m * 16 + cc;
      uint2 st;
      st.x = cvtpk_bf16(acc[m][n][0], acc[m][n][1]);
      st.y = cvtpk_bf16(acc[m][n][2], acc[m][n][3]);
      if (row < M) *(uint2*)(C + (size_t)row * Nc + nblk + wn + n * 16 + q * 4) = st;
      pls[m] += acc[m][n][0] * s0 + acc[m][n][1] * s1 + acc[m][n][2] * s2 + acc[m][n][3] * s3;
      pld[m] += acc[m][n][0] * d0 + acc[m][n][1] * d1 + acc[m][n][2] * d2 + acc[m][n][3] * d3;
    }
  }

  // reduce over q (cols within wave), then across the two wn-halves via LDS
#pragma unroll
  for (int m = 0; m < 4; ++m) {
    pls[m] += __shfl_xor(pls[m], 16, 64);
    pls[m] += __shfl_xor(pls[m], 32, 64);
    pld[m] += __shfl_xor(pld[m], 16, 64);
    pld[m] += __shfl_xor(pld[m], 32, 64);
  }
  float* sred = (float*)As;   // 512 floats, As is free after last barrier
  if (lane < 16) {
#pragma unroll
    for (int m = 0; m < 4; ++m) {
      int idx = ((wv & 1) * 4 + m) * 32 + cc * 2 + (wv >> 1);
      sred[idx] = pls[m];
      sred[256 + idx] = pld[m];
    }
  }
  __syncthreads();
  if (wv < 2) {
    int m = lane >> 4, ccc = lane & 15;
    int row = mblk + wv * 64 + m * 16 + ccc;
    int idx = (wv * 4 + m) * 32 + ccc * 2;
    if (row < M) {
      als[(size_t)row * alsStride + blockIdx.y] = sred[idx] + sred[idx + 1];
      ald[(size_t)row * alsStride + blockIdx.y] = sred[256 + idx] + sred[256 + idx + 1];
    }
  }
}

// GAT layer-1 softmax + aggregation: one block per node, one WAVE per head.
__global__ __launch_bounds__(256) void k_agg1(
    const u16* __restrict__ xh1, const float* __restrict__ als, const float* __restrict__ ald,
    const int* __restrict__ offs, const int* __restrict__ csr,
    const u16* __restrict__ canon, u16* __restrict__ h1)
{
  const int lane = threadIdx.x & 63;
  const int hd = threadIdx.x >> 6;
  const int n = blockIdx.x;
  int off0 = offs[n], off1 = offs[n + 1];
  off0 = clampi(off0, 0, ETOT);
  off1 = clampi(off1, off0, ETOT);
  const float ad = ald[(size_t)n * 4 + hd];
  const int deg = off1 - off0;
  const u16* xb = xh1 + hd * 128 + lane * 2;

  float o0 = 0.f, o1 = 0.f;
  if (deg <= 64) {
    int s = 0;
    float e = -1e30f;
    if (lane < deg) {
      s = clampi(csr[off0 + lane], 0, NSEQ - 1);
      float t = als[(size_t)s * 4 + hd] + ad;
      e = t > 0.f ? t : 0.2f * t;
    }
    float mx = e;
#pragma unroll
    for (int off = 32; off >= 1; off >>= 1) mx = fmaxf(mx, __shfl_xor(mx, off, 64));
    float ex = (lane < deg) ? __expf(e - mx) : 0.f;
    float sm = ex;
#pragma unroll
    for (int off = 32; off >= 1; off >>= 1) sm += __shfl_xor(sm, off, 64);
    const float a = ex * fast_rcp(sm + 1e-16f);
    const int sofs = s * 512;
#pragma unroll 4
    for (int j = 0; j < deg; ++j) {
      int so = __builtin_amdgcn_readlane(sofs, j);
      float aa = __int_as_float(__builtin_amdgcn_readlane(__float_as_int(a), j));
      u32 xv = *(const u32*)(xb + so);
      o0 += aa * bf2f((u16)(xv & 0xffffu));
      o1 += aa * bf2f((u16)(xv >> 16));
    }
  } else {
    float mx = -1e30f;
    for (int k = off0 + lane; k < off1; k += 64) {
      int s = clampi(csr[k], 0, NSEQ - 1);
      float e = als[(size_t)s * 4 + hd] + ad;
      e = e > 0.f ? e : 0.2f * e;
      mx = fmaxf(mx, e);
    }
#pragma unroll
    for (int off = 32; off >= 1; off >>= 1) mx = fmaxf(mx, __shfl_xor(mx, off, 64));
    float sm = 0.f;
    for (int k = off0 + lane; k < off1; k += 64) {
      int s = clampi(csr[k], 0, NSEQ - 1);
      float e = als[(size_t)s * 4 + hd] + ad;
      e = e > 0.f ? e : 0.2f * e;
      sm += __expf(e - mx);
    }
#pragma unroll
    for (int off = 32; off >= 1; off >>= 1) sm += __shfl_xor(sm, off, 64);
    const float rd = fast_rcp(sm + 1e-16f);
#pragma unroll 4
    for (int k = off0; k < off1; ++k) {
      int s = clampi(csr[k], 0, NSEQ - 1);
      float e = als[(size_t)s * 4 + hd] + ad;
      e = e > 0.f ? e : 0.2f * e;
      float a = __expf(e - mx) * rd;
      u32 xv = *(const u32*)(xb + (size_t)s * 512);
      o0 += a * bf2f((u16)(xv & 0xffffu));
      o1 += a * bf2f((u16)(xv >> 16));
    }
  }
  o0 += bf2f(canon[OFF_B1 + hd * 128 + lane * 2]);
  o1 += bf2f(canon[OFF_B1 + hd * 128 + lane * 2 + 1]);
  o0 = o0 > 0.f ? o0 : 0.f;
  o1 = o1 > 0.f ? o1 : 0.f;
  u32 pk = (u32)f2bf(o0) | ((u32)f2bf(o1) << 16);
  *(u32*)(h1 + (size_t)n * 512 + hd * 128 + lane * 2) = pk;
}

// GAT layer-2 aggregation + FUSED FC: wave holds full h2 row (lane = 2 feats),
// 10-class dot via shuffle reduce, direct output store.
__global__ __launch_bounds__(256) void k_agg2(
    const u16* __restrict__ xh2, const float* __restrict__ als2, const float* __restrict__ ald2,
    const int* __restrict__ offs, const int* __restrict__ csr,
    const u16* __restrict__ canon, void* __restrict__ out, const int* __restrict__ flag)
{
  const int lane = threadIdx.x & 63;
  const int n = blockIdx.x * 4 + (threadIdx.x >> 6);
  int off0 = offs[n], off1 = offs[n + 1];
  off0 = clampi(off0, 0, ETOT);
  off1 = clampi(off1, off0, ETOT);
  const float adn = ald2[n];
  const int deg = off1 - off0;

  float o0 = 0.f, o1 = 0.f;
  if (deg <= 64) {
    int s = 0;
    float e = -1e30f;
    if (lane < deg) {
      s = clampi(csr[off0 + lane], 0, NSEQ - 1);
      float t = als2[s] + adn;
      e = t > 0.f ? t : 0.2f * t;
    }
    float mx = e;
#pragma unroll
    for (int off = 32; off >= 1; off >>= 1) mx = fmaxf(mx, __shfl_xor(mx, off, 64));
    float ex = (lane < deg) ? __expf(e - mx) : 0.f;
    float sm = ex;
#pragma unroll
    for (int off = 32; off >= 1; off >>= 1) sm += __shfl_xor(sm, off, 64);
    const float a = ex * fast_rcp(sm + 1e-16f);
    const int sofs = s * 128;
#pragma unroll 4
    for (int j = 0; j < deg; ++j) {
      int so = __builtin_amdgcn_readlane(sofs, j);
      float aa = __int_as_float(__builtin_amdgcn_readlane(__float_as_int(a), j));
      u32 xv = *(const u32*)(xh2 + so + lane * 2);
      o0 += aa * bf2f((u16)(xv & 0xffffu));
      o1 += aa * bf2f((u16)(xv >> 16));
    }
  } else {
    float mx = -1e30f;
    for (int k = off0 + lane; k < off1; k += 64) {
      float e = als2[clampi(csr[k], 0, NSEQ - 1)] + adn;
      e = e > 0.f ? e : 0.2f * e;
      mx = fmaxf(mx, e);
    }
#pragma unroll
    for (int off = 32; off >= 1; off >>= 1) mx = fmaxf(mx, __shfl_xor(mx, off, 64));
    float sm = 0.f;
    for (int k = off0 + lane; k < off1; k += 64) {
      float e = als2[clampi(csr[k], 0, NSEQ - 1)] + adn;
      e = e > 0.f ? e : 0.2f * e;
      sm += __expf(e - mx);
    }
#pragma unroll
    for (int off = 32; off >= 1; off >>= 1) sm += __shfl_xor(sm, off, 64);
    float rd = fast_rcp(sm + 1e-16f);
#pragma unroll 4
    for (int k = off0; k < off1; ++k) {
      int s = clampi(csr[k], 0, NSEQ - 1);
      float e = als2[s] + adn;
      e = e > 0.f ? e : 0.2f * e;
      float a = __expf(e - mx) * rd;
      u32 xv = *(const u32*)(xh2 + (size_t)s * 128 + lane * 2);
      o0 += a * bf2f((u16)(xv & 0xffffu));
      o1 += a * bf2f((u16)(xv >> 16));
    }
  }
  o0 += bf2f(canon[OFF_B2 + lane * 2]);     o0 = o0 > 0.f ? o0 : 0.f;
  o1 += bf2f(canon[OFF_B2 + lane * 2 + 1]); o1 = o1 > 0.f ? o1 : 0.f;

  // fused FC: h2 row lives in (o0,o1) across the wave
  float res[10];
#pragma unroll
  for (int cls = 0; cls < 10; ++cls) {
    float p = o0 * bf2f(canon[OFF_WFC + cls * 128 + lane * 2]) +
              o1 * bf2f(canon[OFF_WFC + cls * 128 + lane * 2 + 1]);
#pragma unroll
    for (int off = 32; off >= 1; off >>= 1) p += __shfl_xor(p, off, 64);
    float v = p + bf2f(canon[OFF_BFC + cls]);
    res[cls] = (fabsf(v) < 1e30f) ? v : 0.f;
  }
  if (flag[0]) {
    if (lane < 5) {
      u32 pk = (u32)f2bf(res[lane * 2]) | ((u32)f2bf(res[lane * 2 + 1]) << 16);
      ((u32*)out)[(size_t)n * 5 + lane] = pk;
    }
  } else {
    if (lane < 10) ((float*)out)[(size_t)n * 10 + lane] = res[lane];
  }
}

// ---- fused setup: zero, histograms (deg + length), scans, scatters ----
__global__ void k_zero_all(int* __restrict__ deg, int* __restrict__ lcnt) {
  int i = blockIdx.x * 256 + threadIdx.x;
  if (i < NSEQ) deg[i] = 0;
  if (i < 64) lcnt[i] = 0;
}

__global__ void k_hist_all(const int* __restrict__ ei, const int* __restrict__ lengths,
                           int* __restrict__ deg, int* __restrict__ lcnt) {
  int i = blockIdx.x * 256 + threadIdx.x;
  if (i < ETOT) {
    int d = (i < EDG) ? ei[EDG + i] : (i - EDG);
    d = clampi(d, 0, NSEQ - 1);
    atomicAdd(&deg[d], 1);
  }
  if (i < NSEQ) atomicAdd(&lcnt[clampi(lengths[i], 1, TT) - 1], 1);
}

// single-block exclusive scan over deg (+ tiny serial length-scan by thread 0)
__global__ __launch_bounds__(1024) void k_scan(const int* __restrict__ deg,
                                               int* __restrict__ offs, int* __restrict__ cur,
                                               const int* __restrict__ lcnt,
                                               int* __restrict__ lcur) {
  __shared__ int wsum[16];
  const int tid = threadIdx.x;
  if (tid == 0) {
    int run = 0;
    for (int i = 0; i < TT; ++i) { lcur[i] = run; run += lcnt[i]; }
  }
  const int lane = tid & 63, wv = tid >> 6;
  const int CHUNK = 20;
  int base = tid * CHUNK;
  int loc[20];
  int s = 0;
#pragma unroll
  for (int i = 0; i < CHUNK; ++i) {
    int idx = base + i;
    int v = (idx < NSEQ) ? deg[idx] : 0;
    loc[i] = s;
    s += v;
  }
  int inc = s;
#pragma unroll
  for (int off = 1; off < 64; off <<= 1) {
    int t2 = __shfl_up(inc, off, 64);
    if (lane >= off) inc += t2;
  }
  if (lane == 63) wsum[wv] = inc;
  __syncthreads();
  int wbase = 0;
  for (int i = 0; i < wv; ++i) wbase += wsum[i];
  int tbase = wbase + inc - s;
#pragma unroll
  for (int i = 0; i < CHUNK; ++i) {
    int idx = base + i;
    if (idx < NSEQ) {
      int st = tbase + loc[i];
      offs[idx] = st;
      cur[idx] = st;
    }
  }
  if (tid == 0) offs[NSEQ] = ETOT;
}

__global__ void k_scatter_all(const int* __restrict__ ei, const int* __restrict__ lengths,
                              int* __restrict__ cur, int* __restrict__ csr,
                              int* __restrict__ lcur, int* __restrict__ lperm) {
  int i = blockIdx.x * 256 + threadIdx.x;
  if (i < ETOT) {
    int s, d;
    if (i < EDG) { s = ei[i]; d = ei[EDG + i]; }
    else { s = i - EDG; d = s; }
    d = clampi(d, 0, NSEQ - 1);
    int pos = atomicAdd(&cur[d], 1);
    pos = clampi(pos, 0, ETOT - 1);
    csr[pos] = s;
  }
  if (i < NSEQ) {
    int b = clampi(lengths[i], 1, TT) - 1;
    int pos = atomicAdd(&lcur[b], 1);
    lperm[clampi(pos, 0, NSEQ - 1)] = i;
  }
}

extern "C" void kernel_launch(void* const* d_in, const int* in_sizes, int n_in,
                              void* d_out, int out_size, void* d_ws, size_t ws_size,
                              hipStream_t stream) {
  (void)in_sizes; (void)n_in;
  const void* x     = d_in[0];
  const int* lengths= (const int*)d_in[1];
  const int* ei     = (const int*)d_in[2];

  const size_t NEED = 45769344u;
  if (ws_size < NEED) {
    k_fill0<<<(out_size + 255) / 256, 256, 0, stream>>>((u16*)d_out, out_size);
    return;
  }

  char* w = (char*)d_ws;
  size_t o = 0;
  auto alloc = [&](size_t b) { char* p = w + o; o += (b + 255) & ~(size_t)255; return p; };
  int*  flag = (int*)  alloc(256);
  u16*  canon= (u16*)  alloc(1048576);
  int*  deg  = (int*)  alloc((size_t)NSEQ * 4);
  int*  offs = (int*)  alloc((size_t)(NSEQ + 1) * 4);
  int*  cur  = (int*)  alloc((size_t)NSEQ * 4);
  int*  csr  = (int*)  alloc((size_t)ETOT * 4);
  float* als1= (float*)alloc((size_t)NSEQ * 4 * 4);
  float* ald1= (float*)alloc((size_t)NSEQ * 4 * 4);
  char* regB = alloc((size_t)NSEQ * 512 * 2);            // xh1 / later xh2,als2,ald2
  u16*  xh1  = (u16*)regB;
  u16*  xh2  = (u16*)regB;
  float* als2= (float*)(regB + (size_t)NSEQ * 128 * 2 + (size_t)NSEQ * 128 * 4);
  float* ald2= als2 + NSEQ;
  char* regA = alloc((size_t)NSEQ * 256 * 2);            // hcat / later h1 (w/ ext)
  u16*  hcat = (u16*)regA;
  u16*  h1   = (u16*)regA;
  alloc((size_t)NSEQ * 256 * 2);                         // h1 extension

  // length-sort scratch lives in regB (dead until k_gemm #1)
  int* lperm = (int*)regB;                       // 80000 B
  int* lcnt  = (int*)(regB + 80128);             // 32 ints
  int* lcur  = (int*)(regB + 80256);             // 32 ints

  k_detect<<<1, 64, 0, stream>>>((const u32*)x, flag);
  CvtArgs ca;
  const int srcIdx[16] = {3, 4, 5, 6, 7, 8, 9, 13, 10, 11, 12, 14, 15, 16, 17, 18};
  const int offv[16]   = {OFF_WIHF, OFF_WHHF, OFF_BF, OFF_WIHB, OFF_WHHB, OFF_BB,
                          OFF_W1, OFF_W2, OFF_A1S, OFF_A1D, OFF_B1,
                          OFF_A2S, OFF_A2D, OFF_B2, OFF_WFC, OFF_BFC};
  const int cntv[16]   = {65536, 65536, 512, 65536, 65536, 512,
                          131072, 65536, 512, 512, 512, 128, 128, 128, 1280, 10};
  for (int i = 0; i < 16; ++i) { ca.src[i] = d_in[srcIdx[i]]; ca.off[i] = offv[i]; ca.cnt[i] = cntv[i]; }
  k_cvt<1><<<256, 256, 0, stream>>>(ca, canon, flag);
  k_cvt<0><<<256, 256, 0, stream>>>(ca, canon, flag);

  // fused setup: zero -> hist(deg+len) -> scan(offs/cur + lcur) -> scatter(csr + lperm)
  k_zero_all<<<(NSEQ + 255) / 256, 256, 0, stream>>>(deg, lcnt);
  k_hist_all<<<(ETOT + 255) / 256, 256, 0, stream>>>(ei, lengths, deg, lcnt);
  k_scan<<<1, 1024, 0, stream>>>(deg, offs, cur, lcnt, lcur);
  k_scatter_all<<<(ETOT + 255) / 256, 256, 0, stream>>>(ei, lengths, cur, csr, lcur, lperm);

  k_lstm<1><<<dim3(313, 2), 512, 0, stream>>>(x, lengths, lperm, canon, hcat, flag);
  k_lstm<0><<<dim3(313, 2), 512, 0, stream>>>(x, lengths, lperm, canon, hcat, flag);

  k_gemm<<<dim3(157, 4), 256, 0, stream>>>(hcat, canon + OFF_W1, xh1, NSEQ, 512, 256,
                                           canon + OFF_A1S, canon + OFF_A1D, als1, ald1, 4);
  k_agg1<<<NSEQ, 256, 0, stream>>>(xh1, als1, ald1, offs, csr, canon, h1);

  k_gemm<<<dim3(157, 1), 256, 0, stream>>>(h1, canon + OFF_W2, xh2, NSEQ, 128, 512,
                                           canon + OFF_A2S, canon + OFF_A2D, als2, ald2, 1);
  k_agg2<<<5000, 256, 0, stream>>>(xh2, als2, ald2, offs, csr, canon, d_out, flag);
}

// Round 3
// 809.287 us; speedup vs baseline: 1.2711x; 1.0164x over previous
//
#include <hip/hip_runtime.h>

#define NSEQ 20000
#define TT 20
#define FD 128
#define EDG 640000
#define ETOT (EDG + NSEQ)

typedef short bf16x8 __attribute__((ext_vector_type(8)));
typedef float f32x4 __attribute__((ext_vector_type(4)));
typedef unsigned short u16;
typedef unsigned int u32;

__device__ __forceinline__ float bf2f(u16 h) {
  union { u32 u; float f; } v; v.u = ((u32)h) << 16; return v.f;
}
__device__ __forceinline__ float bf_lo(u32 w) {
  union { u32 u; float f; } v; v.u = w << 16; return v.f;
}
__device__ __forceinline__ float bf_hi(u32 w) {
  union { u32 u; float f; } v; v.u = w & 0xffff0000u; return v.f;
}
__device__ __forceinline__ u16 f2bf(float f) {
  union { float f; u32 u; } v; v.f = f;
  u32 u = v.u;
  return (u16)((u + 0x7fffu + ((u >> 16) & 1u)) >> 16);
}
// v_rcp_f32: ~1ulp approx reciprocal, 1 instr instead of full-precision div (~9 instr)
__device__ __forceinline__ float fast_rcp(float x) {
  float r; asm("v_rcp_f32 %0, %1" : "=v"(r) : "v"(x)); return r;
}
// v_exp_f32: 2^x, single trans-pipe op (log2e pre-folded into weights)
__device__ __forceinline__ float fast_ex2(float x) {
  float r; asm("v_exp_f32 %0, %1" : "=v"(r) : "v"(x)); return r;
}
// packed fp32->bf16 (RNE), 2 elems/instr; lo = first arg
__device__ __forceinline__ u32 cvtpk_bf16(float a, float b) {
  u32 r; asm("v_cvt_pk_bf16_f32 %0, %1, %2" : "=v"(r) : "v"(a), "v"(b)); return r;
}
__device__ __forceinline__ float fast_rcpp(float x) { return fast_rcp(x); }
__device__ __forceinline__ int clampi(int v, int lo, int hi) {
  return v < lo ? lo : (v > hi ? hi : v);
}

// generic loaders over raw input (BF=1: bf16, BF=0: fp32)
template<int BF>
__device__ __forceinline__ bf16x8 ld8(const void* p, size_t i) {
  if (BF) return *(const bf16x8*)((const u16*)p + i);
  f32x4 a = *(const f32x4*)((const float*)p + i);
  f32x4 b = *(const f32x4*)((const float*)p + i + 4);
  union { u32 w[4]; bf16x8 v; } u;
  u.w[0] = cvtpk_bf16(a[0], a[1]);
  u.w[1] = cvtpk_bf16(a[2], a[3]);
  u.w[2] = cvtpk_bf16(b[0], b[1]);
  u.w[3] = cvtpk_bf16(b[2], b[3]);
  return u.v;
}

// canonical-weights element offsets (u16 units) inside the canon block
#define OFF_WIHF 0
#define OFF_WHHF 65536
#define OFF_BF   131072
#define OFF_WIHB 131584
#define OFF_WHHB 197120
#define OFF_BB   262656
#define OFF_W1   263168
#define OFF_W2   394240
#define OFF_A1S  459776
#define OFF_A1D  460288
#define OFF_B1   460800
#define OFF_A2S  461312
#define OFF_A2D  461440
#define OFF_B2   461568
#define OFF_WFC  461696
#define OFF_BFC  462976

// fused setup stage A: zero deg/lcnt + dtype detect (block 0, wave 0)
__global__ void k_detect_zero(const u32* __restrict__ xw, int* __restrict__ flag,
                              int* __restrict__ deg, int* __restrict__ lcnt) {
  int i = blockIdx.x * 256 + threadIdx.x;
  if (i < NSEQ) deg[i] = 0;
  if (i < 64) lcnt[i] = 0;
  if (blockIdx.x == 0 && threadIdx.x < 64) {
    u16 lo = (u16)(xw[threadIdx.x] & 0xffffu);
    int e = (lo >> 7) & 0xff;
    unsigned long long m = __ballot(e >= 100 && e <= 140);
    if (threadIdx.x == 0) flag[0] = (__popcll(m) >= 32) ? 1 : 0;
  }
}

struct CvtArgs {
  const void* src[16];
  int off[16];
  int cnt[16];
  int wt[16];   // 0: plain, 1: LSTM W (gate=(i>>14)&3), 2: LSTM bias (gate=(i>>7)&3)
};

// LSTM weights pre-scaled by -log2e (gates i,f,o) / +2*log2e (gate g) so the
// nonlinearity uses bare v_exp_f32 (2^x) with no feeding v_mul.
template<int BF>
__global__ void k_cvt(CvtArgs a, u16* __restrict__ canon, const int* __restrict__ flag) {
  if (flag[0] != BF) return;
  int idx = blockIdx.x * 256 + threadIdx.x;
  int stride = gridDim.x * 256;
#pragma unroll 1
  for (int s = 0; s < 16; ++s) {
    const void* sp = a.src[s];
    int n = a.cnt[s], off = a.off[s], wt = a.wt[s];
    for (int i = idx; i < n; i += stride) {
      float v = BF ? bf2f(((const u16*)sp)[i]) : ((const float*)sp)[i];
      if (wt) {
        int gate = (wt == 1) ? ((i >> 14) & 3) : ((i >> 7) & 3);
        v *= (gate == 2) ? 2.885390082f : -1.442695041f;
      }
      canon[off + i] = f2bf(v);
    }
  }
}

__global__ void k_fill0(u16* __restrict__ out, int n) {
  int i = blockIdx.x * 256 + threadIdx.x;
  if (i < n) out[i] = 0;
}

// ---------------------------------------------------------------------------
// Fused BiLSTM. Blocks take 64 length-sorted seqs; LONGEST blocks dispatch
// FIRST. One barrier per step via double-buffered Ax/Ah; x(t+1) prefetch
// issued before the MFMA m-loop. SWAPPED-OPERAND MFMA: D[i=gatecol][j=seq].
// Gate pre-activations arrive pre-scaled (canon weights folded with log2e):
// acc = {-log2e*i, -log2e*f, 2log2e*g, -log2e*o}. Nonlinearity uses fused-rcp
// algebra: 7 trans ops/cell (5 exp2 + 2 rcp) instead of 10.
// ---------------------------------------------------------------------------
template<int BF>
__global__ __launch_bounds__(512, 2) void k_lstm(
    const void* __restrict__ x, const int* __restrict__ lengths,
    const int* __restrict__ lperm,
    const u16* __restrict__ canon, u16* __restrict__ hcat,
    const int* __restrict__ flag)
{
  if (flag[0] != BF) return;
  __shared__ u16 Ax[2][64 * 128];
  __shared__ u16 Ah[2][64 * 128];
  __shared__ int lenS[64];
  __shared__ int seqS[64];
  __shared__ int sMax;

  const int tid = threadIdx.x;
  const int wv = tid >> 6;
  const int lane = tid & 63;
  const int q = lane >> 4;
  const int cc = lane & 15;
  const int dir = blockIdx.y;
  const int b0 = (gridDim.x - 1 - blockIdx.x) * 64;

  const u16* Wi = canon + (dir ? OFF_WIHB : OFF_WIHF);
  const u16* Wh = canon + (dir ? OFF_WHHB : OFF_WHHF);
  const u16* bb = canon + (dir ? OFF_BB : OFF_BF);

  // Weight fragments (A-operand): lane&15 = gate col, k = q*8+j.
  bf16x8 wih[4][4], whh[4][4];
  uint2 bvp[4];  // packed bf16 bias for cols wv*16+q*4 .. +3, per gate
#pragma unroll
  for (int g = 0; g < 4; ++g) {
    int row = g * 128 + wv * 16 + cc;
#pragma unroll
    for (int kt = 0; kt < 4; ++kt) {
      wih[g][kt] = *(const bf16x8*)(Wi + row * 128 + kt * 32 + q * 8);
      whh[g][kt] = *(const bf16x8*)(Wh + row * 128 + kt * 32 + q * 8);
    }
    bvp[g] = *(const uint2*)(bb + g * 128 + wv * 16 + q * 4);
  }

  if (tid < 64) {
    int s = lperm[clampi(b0 + tid, 0, NSEQ - 1)];
    s = clampi(s, 0, NSEQ - 1);
    seqS[tid] = s;
    int L = clampi(lengths[s], 1, TT);
    lenS[tid] = L;
#pragma unroll
    for (int off = 32; off >= 1; off >>= 1) L = max(L, __shfl_xor(L, off, 64));
    if (tid == 0) sMax = L;
  }
  {
    f32x4 zz = {0.f, 0.f, 0.f, 0.f};
    f32x4* p = (f32x4*)Ah[0];
    for (int i = tid; i < 1024; i += 512) p[i] = zz;   // h0 = 0
  }
  __syncthreads();

  const int tmax = sMax;

  // per-lane seq lengths (seq = m*16+cc; uniform over q,r)
  int lenq[4];
#pragma unroll
  for (int m = 0; m < 4; ++m) lenq[m] = lenS[m * 16 + cc];

  const int lrow = tid >> 3;
  const int lj = tid & 7;
  const int sL = seqS[lrow];
  const int lenL = lenS[lrow];
  const size_t xbase = (size_t)sL * (TT * FD);
  const int ax0 = lrow * 128 + ((lj ^ (lrow & 15)) * 8);
  const int ax1 = lrow * 128 + (((lj + 8) ^ (lrow & 15)) * 8);

  // hoisted XOR-swizzle offsets (constant over t)
  int rofs[4];
#pragma unroll
  for (int kt = 0; kt < 4; ++kt) rofs[kt] = cc * 128 + (((4 * kt + q) ^ cc) * 8);
  const int awbase = cc * 128 + (((wv * 2 + (q >> 1)) ^ cc) * 8) + (q & 1) * 4;

  {  // stage x(0) into Ax[0]
    int t0 = dir ? (lenL - 1) : 0;
    bf16x8 d0 = ld8<BF>(x, xbase + t0 * FD + lj * 8);
    bf16x8 d1 = ld8<BF>(x, xbase + t0 * FD + (lj + 8) * 8);
    *(bf16x8*)&Ax[0][ax0] = d0;
    *(bf16x8*)&Ax[0][ax1] = d1;
  }
  float c[4][4] = {};
  int cb = 0;
  __syncthreads();

#pragma unroll 1
  for (int t = 0; t < tmax; ++t) {
    const u16* Axr = Ax[cb];
    u16* Axw = Ax[cb ^ 1];
    const u16* Ahr = Ah[cb];
    u16* Ahw = Ah[cb ^ 1];

    // issue x(t+1) prefetch FIRST: its latency hides behind the MFMA m-loop
    bf16x8 d0 = {}, d1 = {};
    const bool more = (t + 1 < tmax);
    if (more) {
      int tn = t + 1;
      int tt2 = dir ? (lenL - 1 - tn) : tn;
      if (tt2 < 0) tt2 = 0;
      d0 = ld8<BF>(x, xbase + tt2 * FD + lj * 8);
      d1 = ld8<BF>(x, xbase + tt2 * FD + (lj + 8) * 8);
    }

#pragma unroll
    for (int m = 0; m < 4; ++m) {
      const int mb = m * 2048;
      f32x4 acc[4];
#pragma unroll
      for (int g = 0; g < 4; ++g) {
        f32x4 vi = {bf_lo(bvp[g].x), bf_hi(bvp[g].x), bf_lo(bvp[g].y), bf_hi(bvp[g].y)};
        acc[g] = vi;
      }
#pragma unroll
      for (int kt = 0; kt < 4; ++kt) {
        bf16x8 b = *(const bf16x8*)&Axr[mb + rofs[kt]];
#pragma unroll
        for (int g = 0; g < 4; ++g)
          acc[g] = __builtin_amdgcn_mfma_f32_16x16x32_bf16(wih[g][kt], b, acc[g], 0, 0, 0);
      }
#pragma unroll
      for (int kt = 0; kt < 4; ++kt) {
        bf16x8 b = *(const bf16x8*)&Ahr[mb + rofs[kt]];
#pragma unroll
        for (int g = 0; g < 4; ++g)
          acc[g] = __builtin_amdgcn_mfma_f32_16x16x32_bf16(whh[g][kt], b, acc[g], 0, 0, 0);
      }

      // fused-rcp nonlinearity; lane-uniform mask; packed b64 writeback
      uint2 hw;
      if (t < lenq[m]) {
        float hf[4];
#pragma unroll
        for (int r = 0; r < 4; ++r) {
          float Ei = fast_ex2(acc[0][r]);          // e^{-i}
          float Ef = fast_ex2(acc[1][r]);          // e^{-f}
          float G  = fast_ex2(acc[2][r]) + 1.0f;   // e^{2g}+1
          float Eo = fast_ex2(acc[3][r]);          // e^{-o}
          float A = 1.0f + Ef, B = 1.0f + Ei;
          float BG = B * G;
          // cn = c*sigm(f) + sigm(i)*tanh(g) = [c*B*G + A*(G-2)]/(A*B*G)
          float num = c[m][r] * BG + (A * G - 2.0f * A);
          float cn = num * fast_rcp(A * BG);
          c[m][r] = cn;
          // h = sigm(o)*tanh(cn) = (C2-2)/((1+Eo)*C2), C2 = e^{2cn}+1
          float C2 = fast_ex2(cn * 2.885390082f) + 1.0f;
          hf[r] = (C2 - 2.0f) * fast_rcp((1.0f + Eo) * C2);
        }
        hw.x = cvtpk_bf16(hf[0], hf[1]);
        hw.y = cvtpk_bf16(hf[2], hf[3]);
      } else {
        hw = *(const uint2*)&Ahr[mb + awbase];   // carry old h
      }
      *(uint2*)&Ahw[mb + awbase] = hw;
    }

    // store prefetched x(t+1) into the OTHER Ax buffer (no reader this step)
    if (more) {
      *(bf16x8*)&Axw[ax0] = d0;
      *(bf16x8*)&Axw[ax1] = d1;
    }
    __syncthreads();   // single barrier per step
    cb ^= 1;
  }

  // epilogue: Ah[cb] holds last-valid h; write to hcat[seq, dir*128:+128]
  for (int i = tid; i < 1024; i += 512) {
    int row = i >> 4, ch = i & 15;
    if (b0 + row < NSEQ) {
      int seq = seqS[row];
      bf16x8 v = *(const bf16x8*)&Ah[cb][row * 128 + ((ch ^ (row & 15)) * 8)];
      *(bf16x8*)(hcat + (size_t)seq * 256 + dir * 128 + ch * 8) = v;
    }
  }
}

// ---------------------------------------------------------------------------
// Tiled bf16 GEMM: C[M,Nc] = A[M,K] * W[Nc,K]^T. Swapped-operand MFMA ->
// lane holds 4 consecutive cols -> dwordx2 C-stores. Fused attention-logit
// epilogue: als[row*stride+by] = sum_col C[row][col]*aS[col] (and aD).
// ---------------------------------------------------------------------------
__global__ __launch_bounds__(256) void k_gemm(
    const u16* __restrict__ A, const u16* __restrict__ W, u16* __restrict__ C,
    int M, int Nc, int K,
    const u16* __restrict__ aS, const u16* __restrict__ aD,
    float* __restrict__ als, float* __restrict__ ald, int alsStride)
{
  __shared__ u16 As[128 * 64];
  __shared__ u16 Bs[128 * 64];
  const int tid = threadIdx.x;
  const int wv = tid >> 6, lane = tid & 63, q = lane >> 4, cc = lane & 15;
  const int mblk = blockIdx.x * 128, nblk = blockIdx.y * 128;
  const int wm = (wv & 1) * 64, wn = (wv >> 1) * 64;

  f32x4 acc[4][4] = {};

  const int srow = tid >> 1;
  const int sc0 = (tid & 1) * 4;
  int arow_g = mblk + srow; if (arow_g > M - 1) arow_g = M - 1;
  const u16* aptr = A + (size_t)arow_g * K + sc0 * 8;
  const u16* bptr = W + (size_t)(nblk + srow) * K + sc0 * 8;

  for (int k0 = 0; k0 < K; k0 += 64) {
#pragma unroll
    for (int cch = 0; cch < 4; ++cch) {
      bf16x8 av = *(const bf16x8*)(aptr + k0 + cch * 8);
      bf16x8 bvv = *(const bf16x8*)(bptr + k0 + cch * 8);
      int ch = sc0 + cch;
      *(bf16x8*)&As[srow * 64 + ((ch ^ (srow & 7)) * 8)] = av;
      *(bf16x8*)&Bs[srow * 64 + ((ch ^ (srow & 7)) * 8)] = bvv;
    }
    __syncthreads();
#pragma unroll
    for (int kt = 0; kt < 2; ++kt) {
      bf16x8 af[4];
#pragma unroll
      for (int m = 0; m < 4; ++m) {
        int row = wm + m * 16 + cc;
        af[m] = *(const bf16x8*)&As[row * 64 + (((4 * kt + q) ^ (row & 7)) * 8)];
      }
#pragma unroll
      for (int n = 0; n < 4; ++n) {
        int rowb = wn + n * 16 + cc;
        bf16x8 bfr = *(const bf16x8*)&Bs[rowb * 64 + (((4 * kt + q) ^ (rowb & 7)) * 8)];
#pragma unroll
        for (int m = 0; m < 4; ++m)
          acc[m][n] = __builtin_amdgcn_mfma_f32_16x16x32_bf16(bfr, af[m], acc[m][n], 0, 0, 0);
      }
    }
    __syncthreads();
  }

  // C-store: lane = (seq row = wm+m*16+cc, cols wn+n*16+q*4..+3) -> dwordx2
  float pls[4] = {}, pld[4] = {};
#pragma unroll
  for (int n = 0; n < 4; ++n) {
    uint2 ws = *(const uint2*)(aS + nblk + wn + n * 16 + q * 4);
    uint2 wd = *(const uint2*)(aD + nblk + wn + n * 16 + q * 4);
    float s0 = bf_lo(ws.x), s1 = bf_hi(ws.x), s2 = bf_lo(ws.y), s3 = bf_hi(ws.y);
    float d0 = bf_lo(wd.x), d1 = bf_hi(wd.x), d2 = bf_lo(wd.y), d3 = bf_hi(wd.y);
#pragma unroll
    for (int m = 0; m < 4; ++m) {
      int row = mblk + wm + m * 16 + cc;
      uint2 st;
      st.x = cvtpk_bf16(acc[m][n][0], acc[m][n][1]);
      st.y = cvtpk_bf16(acc[m][n][2], acc[m][n][3]);
      if (row < M) *(uint2*)(C + (size_t)row * Nc + nblk + wn + n * 16 + q * 4) = st;
      pls[m] += acc[m][n][0] * s0 + acc[m][n][1] * s1 + acc[m][n][2] * s2 + acc[m][n][3] * s3;
      pld[m] += acc[m][n][0] * d0 + acc[m][n][1] * d1 + acc[m][n][2] * d2 + acc[m][n][3] * d3;
    }
  }

  // reduce over q (cols within wave), then across the two wn-halves via LDS
#pragma unroll
  for (int m = 0; m < 4; ++m) {
    pls[m] += __shfl_xor(pls[m], 16, 64);
    pls[m] += __shfl_xor(pls[m], 32, 64);
    pld[m] += __shfl_xor(pld[m], 16, 64);
    pld[m] += __shfl_xor(pld[m], 32, 64);
  }
  float* sred = (float*)As;   // 512 floats, As is free after last barrier
  if (lane < 16) {
#pragma unroll
    for (int m = 0; m < 4; ++m) {
      int idx = ((wv & 1) * 4 + m) * 32 + cc * 2 + (wv >> 1);
      sred[idx] = pls[m];
      sred[256 + idx] = pld[m];
    }
  }
  __syncthreads();
  if (wv < 2) {
    int m = lane >> 4, ccc = lane & 15;
    int row = mblk + wv * 64 + m * 16 + ccc;
    int idx = (wv * 4 + m) * 32 + ccc * 2;
    if (row < M) {
      als[(size_t)row * alsStride + blockIdx.y] = sred[idx] + sred[idx + 1];
      ald[(size_t)row * alsStride + blockIdx.y] = sred[256 + idx] + sred[256 + idx + 1];
    }
  }
}

// GAT layer-1 softmax + aggregation: one block per node, one WAVE per head.
__global__ __launch_bounds__(256) void k_agg1(
    const u16* __restrict__ xh1, const float* __restrict__ als, const float* __restrict__ ald,
    const int* __restrict__ offs, const int* __restrict__ csr,
    const u16* __restrict__ canon, u16* __restrict__ h1)
{
  const int lane = threadIdx.x & 63;
  const int hd = threadIdx.x >> 6;
  const int n = blockIdx.x;
  int off0 = offs[n], off1 = offs[n + 1];
  off0 = clampi(off0, 0, ETOT);
  off1 = clampi(off1, off0, ETOT);
  const float ad = ald[(size_t)n * 4 + hd];
  const int deg = off1 - off0;
  const u16* xb = xh1 + hd * 128 + lane * 2;

  float o0 = 0.f, o1 = 0.f;
  if (deg <= 64) {
    int s = 0;
    float e = -1e30f;
    if (lane < deg) {
      s = clampi(csr[off0 + lane], 0, NSEQ - 1);
      float t = als[(size_t)s * 4 + hd] + ad;
      e = t > 0.f ? t : 0.2f * t;
    }
    float mx = e;
#pragma unroll
    for (int off = 32; off >= 1; off >>= 1) mx = fmaxf(mx, __shfl_xor(mx, off, 64));
    float ex = (lane < deg) ? __expf(e - mx) : 0.f;
    float sm = ex;
#pragma unroll
    for (int off = 32; off >= 1; off >>= 1) sm += __shfl_xor(sm, off, 64);
    const float a = ex * fast_rcp(sm + 1e-16f);
    const int sofs = s * 512;
#pragma unroll 4
    for (int j = 0; j < deg; ++j) {
      int so = __builtin_amdgcn_readlane(sofs, j);
      float aa = __int_as_float(__builtin_amdgcn_readlane(__float_as_int(a), j));
      u32 xv = *(const u32*)(xb + so);
      o0 += aa * bf2f((u16)(xv & 0xffffu));
      o1 += aa * bf2f((u16)(xv >> 16));
    }
  } else {
    float mx = -1e30f;
    for (int k = off0 + lane; k < off1; k += 64) {
      int s = clampi(csr[k], 0, NSEQ - 1);
      float e = als[(size_t)s * 4 + hd] + ad;
      e = e > 0.f ? e : 0.2f * e;
      mx = fmaxf(mx, e);
    }
#pragma unroll
    for (int off = 32; off >= 1; off >>= 1) mx = fmaxf(mx, __shfl_xor(mx, off, 64));
    float sm = 0.f;
    for (int k = off0 + lane; k < off1; k += 64) {
      int s = clampi(csr[k], 0, NSEQ - 1);
      float e = als[(size_t)s * 4 + hd] + ad;
      e = e > 0.f ? e : 0.2f * e;
      sm += __expf(e - mx);
    }
#pragma unroll
    for (int off = 32; off >= 1; off >>= 1) sm += __shfl_xor(sm, off, 64);
    const float rd = fast_rcp(sm + 1e-16f);
#pragma unroll 4
    for (int k = off0; k < off1; ++k) {
      int s = clampi(csr[k], 0, NSEQ - 1);
      float e = als[(size_t)s * 4 + hd] + ad;
      e = e > 0.f ? e : 0.2f * e;
      float a = __expf(e - mx) * rd;
      u32 xv = *(const u32*)(xb + (size_t)s * 512);
      o0 += a * bf2f((u16)(xv & 0xffffu));
      o1 += a * bf2f((u16)(xv >> 16));
    }
  }
  o0 += bf2f(canon[OFF_B1 + hd * 128 + lane * 2]);
  o1 += bf2f(canon[OFF_B1 + hd * 128 + lane * 2 + 1]);
  o0 = o0 > 0.f ? o0 : 0.f;
  o1 = o1 > 0.f ? o1 : 0.f;
  u32 pk = (u32)f2bf(o0) | ((u32)f2bf(o1) << 16);
  *(u32*)(h1 + (size_t)n * 512 + hd * 128 + lane * 2) = pk;
}

// GAT layer-2 aggregation + FUSED FC: wave holds full h2 row (lane = 2 feats),
// 10-class dot via shuffle reduce, direct output store.
__global__ __launch_bounds__(256) void k_agg2(
    const u16* __restrict__ xh2, const float* __restrict__ als2, const float* __restrict__ ald2,
    const int* __restrict__ offs, const int* __restrict__ csr,
    const u16* __restrict__ canon, void* __restrict__ out, const int* __restrict__ flag)
{
  const int lane = threadIdx.x & 63;
  const int n = blockIdx.x * 4 + (threadIdx.x >> 6);
  int off0 = offs[n], off1 = offs[n + 1];
  off0 = clampi(off0, 0, ETOT);
  off1 = clampi(off1, off0, ETOT);
  const float adn = ald2[n];
  const int deg = off1 - off0;

  float o0 = 0.f, o1 = 0.f;
  if (deg <= 64) {
    int s = 0;
    float e = -1e30f;
    if (lane < deg) {
      s = clampi(csr[off0 + lane], 0, NSEQ - 1);
      float t = als2[s] + adn;
      e = t > 0.f ? t : 0.2f * t;
    }
    float mx = e;
#pragma unroll
    for (int off = 32; off >= 1; off >>= 1) mx = fmaxf(mx, __shfl_xor(mx, off, 64));
    float ex = (lane < deg) ? __expf(e - mx) : 0.f;
    float sm = ex;
#pragma unroll
    for (int off = 32; off >= 1; off >>= 1) sm += __shfl_xor(sm, off, 64);
    const float a = ex * fast_rcp(sm + 1e-16f);
    const int sofs = s * 128;
#pragma unroll 4
    for (int j = 0; j < deg; ++j) {
      int so = __builtin_amdgcn_readlane(sofs, j);
      float aa = __int_as_float(__builtin_amdgcn_readlane(__float_as_int(a), j));
      u32 xv = *(const u32*)(xh2 + so + lane * 2);
      o0 += aa * bf2f((u16)(xv & 0xffffu));
      o1 += aa * bf2f((u16)(xv >> 16));
    }
  } else {
    float mx = -1e30f;
    for (int k = off0 + lane; k < off1; k += 64) {
      float e = als2[clampi(csr[k], 0, NSEQ - 1)] + adn;
      e = e > 0.f ? e : 0.2f * e;
      mx = fmaxf(mx, e);
    }
#pragma unroll
    for (int off = 32; off >= 1; off >>= 1) mx = fmaxf(mx, __shfl_xor(mx, off, 64));
    float sm = 0.f;
    for (int k = off0 + lane; k < off1; k += 64) {
      float e = als2[clampi(csr[k], 0, NSEQ - 1)] + adn;
      e = e > 0.f ? e : 0.2f * e;
      sm += __expf(e - mx);
    }
#pragma unroll
    for (int off = 32; off >= 1; off >>= 1) sm += __shfl_xor(sm, off, 64);
    float rd = fast_rcp(sm + 1e-16f);
#pragma unroll 4
    for (int k = off0; k < off1; ++k) {
      int s = clampi(csr[k], 0, NSEQ - 1);
      float e = als2[s] + adn;
      e = e > 0.f ? e : 0.2f * e;
      float a = __expf(e - mx) * rd;
      u32 xv = *(const u32*)(xh2 + (size_t)s * 128 + lane * 2);
      o0 += a * bf2f((u16)(xv & 0xffffu));
      o1 += a * bf2f((u16)(xv >> 16));
    }
  }
  o0 += bf2f(canon[OFF_B2 + lane * 2]);     o0 = o0 > 0.f ? o0 : 0.f;
  o1 += bf2f(canon[OFF_B2 + lane * 2 + 1]); o1 = o1 > 0.f ? o1 : 0.f;

  // fused FC: h2 row lives in (o0,o1) across the wave
  float res[10];
#pragma unroll
  for (int cls = 0; cls < 10; ++cls) {
    float p = o0 * bf2f(canon[OFF_WFC + cls * 128 + lane * 2]) +
              o1 * bf2f(canon[OFF_WFC + cls * 128 + lane * 2 + 1]);
#pragma unroll
    for (int off = 32; off >= 1; off >>= 1) p += __shfl_xor(p, off, 64);
    float v = p + bf2f(canon[OFF_BFC + cls]);
    res[cls] = (fabsf(v) < 1e30f) ? v : 0.f;
  }
  if (flag[0]) {
    if (lane < 5) {
      u32 pk = (u32)f2bf(res[lane * 2]) | ((u32)f2bf(res[lane * 2 + 1]) << 16);
      ((u32*)out)[(size_t)n * 5 + lane] = pk;
    }
  } else {
    if (lane < 10) ((float*)out)[(size_t)n * 10 + lane] = res[lane];
  }
}

__global__ void k_hist_all(const int* __restrict__ ei, const int* __restrict__ lengths,
                           int* __restrict__ deg, int* __restrict__ lcnt) {
  int i = blockIdx.x * 256 + threadIdx.x;
  if (i < ETOT) {
    int d = (i < EDG) ? ei[EDG + i] : (i - EDG);
    d = clampi(d, 0, NSEQ - 1);
    atomicAdd(&deg[d], 1);
  }
  if (i < NSEQ) atomicAdd(&lcnt[clampi(lengths[i], 1, TT) - 1], 1);
}

// single-block exclusive scan over deg (+ tiny serial length-scan by thread 0)
__global__ __launch_bounds__(1024) void k_scan(const int* __restrict__ deg,
                                               int* __restrict__ offs, int* __restrict__ cur,
                                               const int* __restrict__ lcnt,
                                               int* __restrict__ lcur) {
  __shared__ int wsum[16];
  const int tid = threadIdx.x;
  if (tid == 0) {
    int run = 0;
    for (int i = 0; i < TT; ++i) { lcur[i] = run; run += lcnt[i]; }
  }
  const int lane = tid & 63, wv = tid >> 6;
  const int CHUNK = 20;
  int base = tid * CHUNK;
  int loc[20];
  int s = 0;
#pragma unroll
  for (int i = 0; i < CHUNK; ++i) {
    int idx = base + i;
    int v = (idx < NSEQ) ? deg[idx] : 0;
    loc[i] = s;
    s += v;
  }
  int inc = s;
#pragma unroll
  for (int off = 1; off < 64; off <<= 1) {
    int t2 = __shfl_up(inc, off, 64);
    if (lane >= off) inc += t2;
  }
  if (lane == 63) wsum[wv] = inc;
  __syncthreads();
  int wbase = 0;
  for (int i = 0; i < wv; ++i) wbase += wsum[i];
  int tbase = wbase + inc - s;
#pragma unroll
  for (int i = 0; i < CHUNK; ++i) {
    int idx = base + i;
    if (idx < NSEQ) {
      int st = tbase + loc[i];
      offs[idx] = st;
      cur[idx] = st;
    }
  }
  if (tid == 0) offs[NSEQ] = ETOT;
}

__global__ void k_scatter_all(const int* __restrict__ ei, const int* __restrict__ lengths,
                              int* __restrict__ cur, int* __restrict__ csr,
                              int* __restrict__ lcur, int* __restrict__ lperm) {
  int i = blockIdx.x * 256 + threadIdx.x;
  if (i < ETOT) {
    int s, d;
    if (i < EDG) { s = ei[i]; d = ei[EDG + i]; }
    else { s = i - EDG; d = s; }
    d = clampi(d, 0, NSEQ - 1);
    int pos = atomicAdd(&cur[d], 1);
    pos = clampi(pos, 0, ETOT - 1);
    csr[pos] = s;
  }
  if (i < NSEQ) {
    int b = clampi(lengths[i], 1, TT) - 1;
    int pos = atomicAdd(&lcur[b], 1);
    lperm[clampi(pos, 0, NSEQ - 1)] = i;
  }
}

extern "C" void kernel_launch(void* const* d_in, const int* in_sizes, int n_in,
                              void* d_out, int out_size, void* d_ws, size_t ws_size,
                              hipStream_t stream) {
  (void)in_sizes; (void)n_in;
  const void* x     = d_in[0];
  const int* lengths= (const int*)d_in[1];
  const int* ei     = (const int*)d_in[2];

  const size_t NEED = 45769344u;
  if (ws_size < NEED) {
    k_fill0<<<(out_size + 255) / 256, 256, 0, stream>>>((u16*)d_out, out_size);
    return;
  }

  char* w = (char*)d_ws;
  size_t o = 0;
  auto alloc = [&](size_t b) { char* p = w + o; o += (b + 255) & ~(size_t)255; return p; };
  int*  flag = (int*)  alloc(256);
  u16*  canon= (u16*)  alloc(1048576);
  int*  deg  = (int*)  alloc((size_t)NSEQ * 4);
  int*  offs = (int*)  alloc((size_t)(NSEQ + 1) * 4);
  int*  cur  = (int*)  alloc((size_t)NSEQ * 4);
  int*  csr  = (int*)  alloc((size_t)ETOT * 4);
  float* als1= (float*)alloc((size_t)NSEQ * 4 * 4);
  float* ald1= (float*)alloc((size_t)NSEQ * 4 * 4);
  char* regB = alloc((size_t)NSEQ * 512 * 2);            // xh1 / later xh2,als2,ald2
  u16*  xh1  = (u16*)regB;
  u16*  xh2  = (u16*)regB;
  float* als2= (float*)(regB + (size_t)NSEQ * 128 * 2 + (size_t)NSEQ * 128 * 4);
  float* ald2= als2 + NSEQ;
  char* regA = alloc((size_t)NSEQ * 256 * 2);            // hcat / later h1 (w/ ext)
  u16*  hcat = (u16*)regA;
  u16*  h1   = (u16*)regA;
  alloc((size_t)NSEQ * 256 * 2);                         // h1 extension

  // length-sort scratch lives in regB (dead until k_gemm #1)
  int* lperm = (int*)regB;                       // 80000 B
  int* lcnt  = (int*)(regB + 80128);             // 32 ints
  int* lcur  = (int*)(regB + 80256);             // 32 ints

  // fused: zero deg/lcnt + dtype detect
  k_detect_zero<<<(NSEQ + 255) / 256, 256, 0, stream>>>((const u32*)x, flag, deg, lcnt);

  CvtArgs ca;
  const int srcIdx[16] = {3, 4, 5, 6, 7, 8, 9, 13, 10, 11, 12, 14, 15, 16, 17, 18};
  const int offv[16]   = {OFF_WIHF, OFF_WHHF, OFF_BF, OFF_WIHB, OFF_WHHB, OFF_BB,
                          OFF_W1, OFF_W2, OFF_A1S, OFF_A1D, OFF_B1,
                          OFF_A2S, OFF_A2D, OFF_B2, OFF_WFC, OFF_BFC};
  const int cntv[16]   = {65536, 65536, 512, 65536, 65536, 512,
                          131072, 65536, 512, 512, 512, 128, 128, 128, 1280, 10};
  const int wtv[16]    = {1, 1, 2, 1, 1, 2, 0, 0, 0, 0, 0, 0, 0, 0, 0, 0};
  for (int i = 0; i < 16; ++i) {
    ca.src[i] = d_in[srcIdx[i]]; ca.off[i] = offv[i]; ca.cnt[i] = cntv[i]; ca.wt[i] = wtv[i];
  }
  k_cvt<1><<<256, 256, 0, stream>>>(ca, canon, flag);
  k_cvt<0><<<256, 256, 0, stream>>>(ca, canon, flag);

  // setup: hist(deg+len) -> scan(offs/cur + lcur) -> scatter(csr + lperm)
  k_hist_all<<<(ETOT + 255) / 256, 256, 0, stream>>>(ei, lengths, deg, lcnt);
  k_scan<<<1, 1024, 0, stream>>>(deg, offs, cur, lcnt, lcur);
  k_scatter_all<<<(ETOT + 255) / 256, 256, 0, stream>>>(ei, lengths, cur, csr, lcur, lperm);

  k_lstm<1><<<dim3(313, 2), 512, 0, stream>>>(x, lengths, lperm, canon, hcat, flag);
  k_lstm<0><<<dim3(313, 2), 512, 0, stream>>>(x, lengths, lperm, canon, hcat, flag);

  k_gemm<<<dim3(157, 4), 256, 0, stream>>>(hcat, canon + OFF_W1, xh1, NSEQ, 512, 256,
                                           canon + OFF_A1S, canon + OFF_A1D, als1, ald1, 4);
  k_agg1<<<NSEQ, 256, 0, stream>>>(xh1, als1, ald1, offs, csr, canon, h1);

  k_gemm<<<dim3(157, 1), 256, 0, stream>>>(h1, canon + OFF_W2, xh2, NSEQ, 128, 512,
                                           canon + OFF_A2S, canon + OFF_A2D, als2, ald2, 1);
  k_agg2<<<5000, 256, 0, stream>>>(xh2, als2, ald2, offs, csr, canon, d_out, flag);
}

// Round 4
// 801.043 us; speedup vs baseline: 1.2842x; 1.0103x over previous
//
#include <hip/hip_runtime.h>

#define NSEQ 20000
#define TT 20
#define FD 128
#define EDG 640000
#define ETOT (EDG + NSEQ)

typedef short bf16x8 __attribute__((ext_vector_type(8)));
typedef float f32x4 __attribute__((ext_vector_type(4)));
typedef unsigned short u16;
typedef unsigned int u32;

__device__ __forceinline__ float bf2f(u16 h) {
  union { u32 u; float f; } v; v.u = ((u32)h) << 16; return v.f;
}
__device__ __forceinline__ float bf_lo(u32 w) {
  union { u32 u; float f; } v; v.u = w << 16; return v.f;
}
__device__ __forceinline__ float bf_hi(u32 w) {
  union { u32 u; float f; } v; v.u = w & 0xffff0000u; return v.f;
}
__device__ __forceinline__ u16 f2bf(float f) {
  union { float f; u32 u; } v; v.f = f;
  u32 u = v.u;
  return (u16)((u + 0x7fffu + ((u >> 16) & 1u)) >> 16);
}
// v_rcp_f32: ~1ulp approx reciprocal, 1 instr instead of full-precision div (~9 instr)
__device__ __forceinline__ float fast_rcp(float x) {
  float r; asm("v_rcp_f32 %0, %1" : "=v"(r) : "v"(x)); return r;
}
// v_exp_f32: 2^x, single trans-pipe op (log2e pre-folded into weights)
__device__ __forceinline__ float fast_ex2(float x) {
  float r; asm("v_exp_f32 %0, %1" : "=v"(r) : "v"(x)); return r;
}
// packed fp32->bf16 (RNE), 2 elems/instr; lo = first arg
__device__ __forceinline__ u32 cvtpk_bf16(float a, float b) {
  u32 r; asm("v_cvt_pk_bf16_f32 %0, %1, %2" : "=v"(r) : "v"(a), "v"(b)); return r;
}
__device__ __forceinline__ int clampi(int v, int lo, int hi) {
  return v < lo ? lo : (v > hi ? hi : v);
}

// generic loaders over raw input (BF=1: bf16, BF=0: fp32)
template<int BF>
__device__ __forceinline__ bf16x8 ld8(const void* p, size_t i) {
  if (BF) return *(const bf16x8*)((const u16*)p + i);
  f32x4 a = *(const f32x4*)((const float*)p + i);
  f32x4 b = *(const f32x4*)((const float*)p + i + 4);
  union { u32 w[4]; bf16x8 v; } u;
  u.w[0] = cvtpk_bf16(a[0], a[1]);
  u.w[1] = cvtpk_bf16(a[2], a[3]);
  u.w[2] = cvtpk_bf16(b[0], b[1]);
  u.w[3] = cvtpk_bf16(b[2], b[3]);
  return u.v;
}

// canonical-weights element offsets (u16 units) inside the canon block
#define OFF_WIHF 0
#define OFF_WHHF 65536
#define OFF_BF   131072
#define OFF_WIHB 131584
#define OFF_WHHB 197120
#define OFF_BB   262656
#define OFF_W1   263168
#define OFF_W2   394240
#define OFF_A1S  459776
#define OFF_A1D  460288
#define OFF_B1   460800
#define OFF_A2S  461312
#define OFF_A2D  461440
#define OFF_B2   461568
#define OFF_WFC  461696
#define OFF_BFC  462976

// fused setup stage A: zero deg/lcnt + dtype detect (block 0, wave 0)
__global__ void k_detect_zero(const u32* __restrict__ xw, int* __restrict__ flag,
                              int* __restrict__ deg, int* __restrict__ lcnt) {
  int i = blockIdx.x * 256 + threadIdx.x;
  if (i < NSEQ) deg[i] = 0;
  if (i < 64) lcnt[i] = 0;
  if (blockIdx.x == 0 && threadIdx.x < 64) {
    u16 lo = (u16)(xw[threadIdx.x] & 0xffffu);
    int e = (lo >> 7) & 0xff;
    unsigned long long m = __ballot(e >= 100 && e <= 140);
    if (threadIdx.x == 0) flag[0] = (__popcll(m) >= 32) ? 1 : 0;
  }
}

struct CvtArgs {
  const void* src[16];
  int off[16];
  int cnt[16];
  int wt[16];   // 0: plain, 1: LSTM W (gate=(i>>14)&3), 2: LSTM bias (gate=(i>>7)&3)
};

// LSTM weights pre-scaled by -log2e (gates i,f,o) / +2*log2e (gate g) so the
// nonlinearity uses bare v_exp_f32 (2^x) with no feeding v_mul.
template<int BF>
__global__ void k_cvt(CvtArgs a, u16* __restrict__ canon, const int* __restrict__ flag) {
  if (flag[0] != BF) return;
  int idx = blockIdx.x * 256 + threadIdx.x;
  int stride = gridDim.x * 256;
#pragma unroll 1
  for (int s = 0; s < 16; ++s) {
    const void* sp = a.src[s];
    int n = a.cnt[s], off = a.off[s], wt = a.wt[s];
    for (int i = idx; i < n; i += stride) {
      float v = BF ? bf2f(((const u16*)sp)[i]) : ((const float*)sp)[i];
      if (wt) {
        int gate = (wt == 1) ? ((i >> 14) & 3) : ((i >> 7) & 3);
        v *= (gate == 2) ? 2.885390082f : -1.442695041f;
      }
      canon[off + i] = f2bf(v);
    }
  }
}

__global__ void k_fill0(u16* __restrict__ out, int n) {
  int i = blockIdx.x * 256 + threadIdx.x;
  if (i < n) out[i] = 0;
}

// ---------------------------------------------------------------------------
// Fused BiLSTM, 128 length-sorted seqs per block (8 m-tiles), LONGEST blocks
// dispatch FIRST (314 blocks -> 1.23 rounds at 1 block/CU). One barrier per
// step via double-buffered Ax/Ah; x(t+1) prefetch issued before the MFMA
// m-loop. SWAPPED-OPERAND MFMA: D[i=gatecol][j=seq]. Gate pre-activations
// arrive pre-scaled (log2e folded in canon): 7 trans ops/cell.
// ---------------------------------------------------------------------------
template<int BF>
__global__ __launch_bounds__(512, 2) void k_lstm(
    const void* __restrict__ x, const int* __restrict__ lengths,
    const int* __restrict__ lperm,
    const u16* __restrict__ canon, u16* __restrict__ hcat,
    const int* __restrict__ flag)
{
  if (flag[0] != BF) return;
  __shared__ u16 Ax[2][128 * 128];
  __shared__ u16 Ah[2][128 * 128];
  __shared__ int lenS[128];
  __shared__ int seqS[128];

  const int tid = threadIdx.x;
  const int wv = tid >> 6;
  const int lane = tid & 63;
  const int q = lane >> 4;
  const int cc = lane & 15;
  const int dir = blockIdx.y;
  const int b0 = (gridDim.x - 1 - blockIdx.x) * 128;   // longest-first

  const u16* Wi = canon + (dir ? OFF_WIHB : OFF_WIHF);
  const u16* Wh = canon + (dir ? OFF_WHHB : OFF_WHHF);
  const u16* bb = canon + (dir ? OFF_BB : OFF_BF);

  // Weight fragments (A-operand): lane&15 = gate col, k = q*8+j. (live in AGPRs)
  bf16x8 wih[4][4], whh[4][4];
  uint2 bvp[4];  // packed bf16 bias for cols wv*16+q*4 .. +3, per gate
#pragma unroll
  for (int g = 0; g < 4; ++g) {
    int row = g * 128 + wv * 16 + cc;
#pragma unroll
    for (int kt = 0; kt < 4; ++kt) {
      wih[g][kt] = *(const bf16x8*)(Wi + row * 128 + kt * 32 + q * 8);
      whh[g][kt] = *(const bf16x8*)(Wh + row * 128 + kt * 32 + q * 8);
    }
    bvp[g] = *(const uint2*)(bb + g * 128 + wv * 16 + q * 4);
  }

  if (tid < 128) {
    int s = lperm[clampi(b0 + tid, 0, NSEQ - 1)];
    s = clampi(s, 0, NSEQ - 1);
    seqS[tid] = s;
    lenS[tid] = clampi(lengths[s], 1, TT);
  }
  {
    f32x4 zz = {0.f, 0.f, 0.f, 0.f};
    f32x4* p = (f32x4*)Ah[0];
    for (int i = tid; i < 2048; i += 512) p[i] = zz;   // h0 = 0
  }
  __syncthreads();

  // sorted slice (clamped dups are the largest index) -> max = last entry
  const int tmax = lenS[127];

  // per-lane seq lengths (seq = m*16+cc; uniform over q,r)
  int lenq[8];
#pragma unroll
  for (int m = 0; m < 8; ++m) lenq[m] = lenS[m * 16 + cc];

  // hoisted staging state: 4 chunks/thread (2048 chunks = 128 rows x 16)
  int axj[4], lenj[4];
  size_t xbj[4];
#pragma unroll
  for (int j = 0; j < 4; ++j) {
    int idx = tid + j * 512;
    int row = idx >> 4, ch = idx & 15;
    axj[j] = row * 128 + ((ch ^ (row & 15)) * 8);
    xbj[j] = (size_t)seqS[row] * (TT * FD) + ch * 8;
    lenj[j] = lenS[row];
  }

  // hoisted XOR-swizzle offsets (constant over t)
  int rofs[4];
#pragma unroll
  for (int kt = 0; kt < 4; ++kt) rofs[kt] = cc * 128 + (((4 * kt + q) ^ cc) * 8);
  const int awbase = cc * 128 + (((wv * 2 + (q >> 1)) ^ cc) * 8) + (q & 1) * 4;

  {  // stage x(0) into Ax[0]
#pragma unroll
    for (int j = 0; j < 4; ++j) {
      int t0 = dir ? (lenj[j] - 1) : 0;
      bf16x8 d = ld8<BF>(x, xbj[j] + t0 * FD);
      *(bf16x8*)&Ax[0][axj[j]] = d;
    }
  }
  float c[8][4] = {};
  int cb = 0;
  __syncthreads();

#pragma unroll 1
  for (int t = 0; t < tmax; ++t) {
    const u16* Axr = Ax[cb];
    u16* Axw = Ax[cb ^ 1];
    const u16* Ahr = Ah[cb];
    u16* Ahw = Ah[cb ^ 1];

    // issue x(t+1) prefetch FIRST: its latency hides behind the MFMA m-loop
    bf16x8 d[4];
    const bool more = (t + 1 < tmax);
    if (more) {
#pragma unroll
      for (int j = 0; j < 4; ++j) {
        int tt2 = dir ? (lenj[j] - 1 - (t + 1)) : (t + 1);
        if (tt2 < 0) tt2 = 0;
        d[j] = ld8<BF>(x, xbj[j] + tt2 * FD);
      }
    }

#pragma unroll
    for (int m = 0; m < 8; ++m) {
      const int mb = m * 2048;
      f32x4 acc[4];
#pragma unroll
      for (int g = 0; g < 4; ++g) {
        f32x4 vi = {bf_lo(bvp[g].x), bf_hi(bvp[g].x), bf_lo(bvp[g].y), bf_hi(bvp[g].y)};
        acc[g] = vi;
      }
#pragma unroll
      for (int kt = 0; kt < 4; ++kt) {
        bf16x8 b = *(const bf16x8*)&Axr[mb + rofs[kt]];
#pragma unroll
        for (int g = 0; g < 4; ++g)
          acc[g] = __builtin_amdgcn_mfma_f32_16x16x32_bf16(wih[g][kt], b, acc[g], 0, 0, 0);
      }
#pragma unroll
      for (int kt = 0; kt < 4; ++kt) {
        bf16x8 b = *(const bf16x8*)&Ahr[mb + rofs[kt]];
#pragma unroll
        for (int g = 0; g < 4; ++g)
          acc[g] = __builtin_amdgcn_mfma_f32_16x16x32_bf16(whh[g][kt], b, acc[g], 0, 0, 0);
      }

      // fused-rcp nonlinearity; lane-uniform mask; packed b64 writeback
      uint2 hw;
      if (t < lenq[m]) {
        float hf[4];
#pragma unroll
        for (int r = 0; r < 4; ++r) {
          float Ei = fast_ex2(acc[0][r]);          // e^{-i}
          float Ef = fast_ex2(acc[1][r]);          // e^{-f}
          float G  = fast_ex2(acc[2][r]) + 1.0f;   // e^{2g}+1
          float Eo = fast_ex2(acc[3][r]);          // e^{-o}
          float A = 1.0f + Ef, B = 1.0f + Ei;
          float BG = B * G;
          float num = c[m][r] * BG + (A * G - 2.0f * A);
          float cn = num * fast_rcp(A * BG);
          c[m][r] = cn;
          float C2 = fast_ex2(cn * 2.885390082f) + 1.0f;
          hf[r] = (C2 - 2.0f) * fast_rcp((1.0f + Eo) * C2);
        }
        hw.x = cvtpk_bf16(hf[0], hf[1]);
        hw.y = cvtpk_bf16(hf[2], hf[3]);
      } else {
        hw = *(const uint2*)&Ahr[mb + awbase];   // carry old h
      }
      *(uint2*)&Ahw[mb + awbase] = hw;
    }

    // store prefetched x(t+1) into the OTHER Ax buffer (no reader this step)
    if (more) {
#pragma unroll
      for (int j = 0; j < 4; ++j) *(bf16x8*)&Axw[axj[j]] = d[j];
    }
    __syncthreads();   // single barrier per step
    cb ^= 1;
  }

  // epilogue: Ah[cb] holds last-valid h; write to hcat[seq, dir*128:+128]
  for (int i = tid; i < 2048; i += 512) {
    int row = i >> 4, ch = i & 15;
    if (b0 + row < NSEQ) {
      int seq = seqS[row];
      bf16x8 v = *(const bf16x8*)&Ah[cb][row * 128 + ((ch ^ (row & 15)) * 8)];
      *(bf16x8*)(hcat + (size_t)seq * 256 + dir * 128 + ch * 8) = v;
    }
  }
}

// ---------------------------------------------------------------------------
// Tiled bf16 GEMM: C[M,Nc] = A[M,K] * W[Nc,K]^T. Swapped-operand MFMA ->
// lane holds 4 consecutive cols -> dwordx2 C-stores. Fused attention-logit
// epilogue: als[row*stride+by] = sum_col C[row][col]*aS[col] (and aD).
// ---------------------------------------------------------------------------
__global__ __launch_bounds__(256) void k_gemm(
    const u16* __restrict__ A, const u16* __restrict__ W, u16* __restrict__ C,
    int M, int Nc, int K,
    const u16* __restrict__ aS, const u16* __restrict__ aD,
    float* __restrict__ als, float* __restrict__ ald, int alsStride)
{
  __shared__ u16 As[128 * 64];
  __shared__ u16 Bs[128 * 64];
  const int tid = threadIdx.x;
  const int wv = tid >> 6, lane = tid & 63, q = lane >> 4, cc = lane & 15;
  const int mblk = blockIdx.x * 128, nblk = blockIdx.y * 128;
  const int wm = (wv & 1) * 64, wn = (wv >> 1) * 64;

  f32x4 acc[4][4] = {};

  const int srow = tid >> 1;
  const int sc0 = (tid & 1) * 4;
  int arow_g = mblk + srow; if (arow_g > M - 1) arow_g = M - 1;
  const u16* aptr = A + (size_t)arow_g * K + sc0 * 8;
  const u16* bptr = W + (size_t)(nblk + srow) * K + sc0 * 8;

  for (int k0 = 0; k0 < K; k0 += 64) {
#pragma unroll
    for (int cch = 0; cch < 4; ++cch) {
      bf16x8 av = *(const bf16x8*)(aptr + k0 + cch * 8);
      bf16x8 bvv = *(const bf16x8*)(bptr + k0 + cch * 8);
      int ch = sc0 + cch;
      *(bf16x8*)&As[srow * 64 + ((ch ^ (srow & 7)) * 8)] = av;
      *(bf16x8*)&Bs[srow * 64 + ((ch ^ (srow & 7)) * 8)] = bvv;
    }
    __syncthreads();
#pragma unroll
    for (int kt = 0; kt < 2; ++kt) {
      bf16x8 af[4];
#pragma unroll
      for (int m = 0; m < 4; ++m) {
        int row = wm + m * 16 + cc;
        af[m] = *(const bf16x8*)&As[row * 64 + (((4 * kt + q) ^ (row & 7)) * 8)];
      }
#pragma unroll
      for (int n = 0; n < 4; ++n) {
        int rowb = wn + n * 16 + cc;
        bf16x8 bfr = *(const bf16x8*)&Bs[rowb * 64 + (((4 * kt + q) ^ (rowb & 7)) * 8)];
#pragma unroll
        for (int m = 0; m < 4; ++m)
          acc[m][n] = __builtin_amdgcn_mfma_f32_16x16x32_bf16(bfr, af[m], acc[m][n], 0, 0, 0);
      }
    }
    __syncthreads();
  }

  // C-store: lane = (seq row = wm+m*16+cc, cols wn+n*16+q*4..+3) -> dwordx2
  float pls[4] = {}, pld[4] = {};
#pragma unroll
  for (int n = 0; n < 4; ++n) {
    uint2 ws = *(const uint2*)(aS + nblk + wn + n * 16 + q * 4);
    uint2 wd = *(const uint2*)(aD + nblk + wn + n * 16 + q * 4);
    float s0 = bf_lo(ws.x), s1 = bf_hi(ws.x), s2 = bf_lo(ws.y), s3 = bf_hi(ws.y);
    float d0 = bf_lo(wd.x), d1 = bf_hi(wd.x), d2 = bf_lo(wd.y), d3 = bf_hi(wd.y);
#pragma unroll
    for (int m = 0; m < 4; ++m) {
      int row = mblk + wm + m * 16 + cc;
      uint2 st;
      st.x = cvtpk_bf16(acc[m][n][0], acc[m][n][1]);
      st.y = cvtpk_bf16(acc[m][n][2], acc[m][n][3]);
      if (row < M) *(uint2*)(C + (size_t)row * Nc + nblk + wn + n * 16 + q * 4) = st;
      pls[m] += acc[m][n][0] * s0 + acc[m][n][1] * s1 + acc[m][n][2] * s2 + acc[m][n][3] * s3;
      pld[m] += acc[m][n][0] * d0 + acc[m][n][1] * d1 + acc[m][n][2] * d2 + acc[m][n][3] * d3;
    }
  }

  // reduce over q (cols within wave), then across the two wn-halves via LDS
#pragma unroll
  for (int m = 0; m < 4; ++m) {
    pls[m] += __shfl_xor(pls[m], 16, 64);
    pls[m] += __shfl_xor(pls[m], 32, 64);
    pld[m] += __shfl_xor(pld[m], 16, 64);
    pld[m] += __shfl_xor(pld[m], 32, 64);
  }
  float* sred = (float*)As;   // 512 floats, As is free after last barrier
  if (lane < 16) {
#pragma unroll
    for (int m = 0; m < 4; ++m) {
      int idx = ((wv & 1) * 4 + m) * 32 + cc * 2 + (wv >> 1);
      sred[idx] = pls[m];
      sred[256 + idx] = pld[m];
    }
  }
  __syncthreads();
  if (wv < 2) {
    int m = lane >> 4, ccc = lane & 15;
    int row = mblk + wv * 64 + m * 16 + ccc;
    int idx = (wv * 4 + m) * 32 + ccc * 2;
    if (row < M) {
      als[(size_t)row * alsStride + blockIdx.y] = sred[idx] + sred[idx + 1];
      ald[(size_t)row * alsStride + blockIdx.y] = sred[256 + idx] + sred[256 + idx + 1];
    }
  }
}

// GAT layer-1 softmax + aggregation: one WAVE per node covering ALL 4 heads
// (4 independent gather loads/edge -> 4x memory ILP; als/ald/csr read once).
__global__ __launch_bounds__(256) void k_agg1(
    const u16* __restrict__ xh1, const float* __restrict__ als, const float* __restrict__ ald,
    const int* __restrict__ offs, const int* __restrict__ csr,
    const u16* __restrict__ canon, u16* __restrict__ h1)
{
  const int lane = threadIdx.x & 63;
  const int n = blockIdx.x * 4 + (threadIdx.x >> 6);
  int off0 = offs[n], off1 = offs[n + 1];
  off0 = clampi(off0, 0, ETOT);
  off1 = clampi(off1, off0, ETOT);
  const int deg = off1 - off0;
  const float4 ad = *(const float4*)(ald + (size_t)n * 4);
  const u16* xb = xh1 + lane * 2;

  float o0 = 0.f, o1 = 0.f, o2 = 0.f, o3 = 0.f, o4 = 0.f, o5 = 0.f, o6 = 0.f, o7 = 0.f;
  if (deg <= 64) {
    int s = 0;
    float e0 = -1e30f, e1 = -1e30f, e2 = -1e30f, e3 = -1e30f;
    if (lane < deg) {
      s = clampi(csr[off0 + lane], 0, NSEQ - 1);
      float4 av = *(const float4*)(als + (size_t)s * 4);
      float t;
      t = av.x + ad.x; e0 = t > 0.f ? t : 0.2f * t;
      t = av.y + ad.y; e1 = t > 0.f ? t : 0.2f * t;
      t = av.z + ad.z; e2 = t > 0.f ? t : 0.2f * t;
      t = av.w + ad.w; e3 = t > 0.f ? t : 0.2f * t;
    }
    float m0 = e0, m1 = e1, m2 = e2, m3 = e3;
#pragma unroll
    for (int off = 32; off >= 1; off >>= 1) {
      m0 = fmaxf(m0, __shfl_xor(m0, off, 64));
      m1 = fmaxf(m1, __shfl_xor(m1, off, 64));
      m2 = fmaxf(m2, __shfl_xor(m2, off, 64));
      m3 = fmaxf(m3, __shfl_xor(m3, off, 64));
    }
    float x0 = (lane < deg) ? __expf(e0 - m0) : 0.f;
    float x1 = (lane < deg) ? __expf(e1 - m1) : 0.f;
    float x2 = (lane < deg) ? __expf(e2 - m2) : 0.f;
    float x3 = (lane < deg) ? __expf(e3 - m3) : 0.f;
    float s0 = x0, s1 = x1, s2 = x2, s3 = x3;
#pragma unroll
    for (int off = 32; off >= 1; off >>= 1) {
      s0 += __shfl_xor(s0, off, 64);
      s1 += __shfl_xor(s1, off, 64);
      s2 += __shfl_xor(s2, off, 64);
      s3 += __shfl_xor(s3, off, 64);
    }
    float a0 = x0 * fast_rcp(s0 + 1e-16f);
    float a1 = x1 * fast_rcp(s1 + 1e-16f);
    float a2 = x2 * fast_rcp(s2 + 1e-16f);
    float a3 = x3 * fast_rcp(s3 + 1e-16f);
    const int sofs = s * 512;
#pragma unroll 2
    for (int j = 0; j < deg; ++j) {
      int so = __builtin_amdgcn_readlane(sofs, j);
      float aa0 = __int_as_float(__builtin_amdgcn_readlane(__float_as_int(a0), j));
      float aa1 = __int_as_float(__builtin_amdgcn_readlane(__float_as_int(a1), j));
      float aa2 = __int_as_float(__builtin_amdgcn_readlane(__float_as_int(a2), j));
      float aa3 = __int_as_float(__builtin_amdgcn_readlane(__float_as_int(a3), j));
      u32 v0 = *(const u32*)(xb + so);
      u32 v1 = *(const u32*)(xb + so + 128);
      u32 v2 = *(const u32*)(xb + so + 256);
      u32 v3 = *(const u32*)(xb + so + 384);
      o0 += aa0 * bf_lo(v0); o1 += aa0 * bf_hi(v0);
      o2 += aa1 * bf_lo(v1); o3 += aa1 * bf_hi(v1);
      o4 += aa2 * bf_lo(v2); o5 += aa2 * bf_hi(v2);
      o6 += aa3 * bf_lo(v3); o7 += aa3 * bf_hi(v3);
    }
  } else {
    float m0 = -1e30f, m1 = -1e30f, m2 = -1e30f, m3 = -1e30f;
    for (int k = off0 + lane; k < off1; k += 64) {
      int s = clampi(csr[k], 0, NSEQ - 1);
      float4 av = *(const float4*)(als + (size_t)s * 4);
      float t;
      t = av.x + ad.x; t = t > 0.f ? t : 0.2f * t; m0 = fmaxf(m0, t);
      t = av.y + ad.y; t = t > 0.f ? t : 0.2f * t; m1 = fmaxf(m1, t);
      t = av.z + ad.z; t = t > 0.f ? t : 0.2f * t; m2 = fmaxf(m2, t);
      t = av.w + ad.w; t = t > 0.f ? t : 0.2f * t; m3 = fmaxf(m3, t);
    }
#pragma unroll
    for (int off = 32; off >= 1; off >>= 1) {
      m0 = fmaxf(m0, __shfl_xor(m0, off, 64));
      m1 = fmaxf(m1, __shfl_xor(m1, off, 64));
      m2 = fmaxf(m2, __shfl_xor(m2, off, 64));
      m3 = fmaxf(m3, __shfl_xor(m3, off, 64));
    }
    float s0 = 0.f, s1 = 0.f, s2 = 0.f, s3 = 0.f;
    for (int k = off0 + lane; k < off1; k += 64) {
      int s = clampi(csr[k], 0, NSEQ - 1);
      float4 av = *(const float4*)(als + (size_t)s * 4);
      float t;
      t = av.x + ad.x; t = t > 0.f ? t : 0.2f * t; s0 += __expf(t - m0);
      t = av.y + ad.y; t = t > 0.f ? t : 0.2f * t; s1 += __expf(t - m1);
      t = av.z + ad.z; t = t > 0.f ? t : 0.2f * t; s2 += __expf(t - m2);
      t = av.w + ad.w; t = t > 0.f ? t : 0.2f * t; s3 += __expf(t - m3);
    }
#pragma unroll
    for (int off = 32; off >= 1; off >>= 1) {
      s0 += __shfl_xor(s0, off, 64);
      s1 += __shfl_xor(s1, off, 64);
      s2 += __shfl_xor(s2, off, 64);
      s3 += __shfl_xor(s3, off, 64);
    }
    float rd0 = fast_rcp(s0 + 1e-16f), rd1 = fast_rcp(s1 + 1e-16f);
    float rd2 = fast_rcp(s2 + 1e-16f), rd3 = fast_rcp(s3 + 1e-16f);
    for (int k = off0; k < off1; ++k) {
      int s = clampi(csr[k], 0, NSEQ - 1);
      float4 av = *(const float4*)(als + (size_t)s * 4);
      float t;
      t = av.x + ad.x; t = t > 0.f ? t : 0.2f * t; float aa0 = __expf(t - m0) * rd0;
      t = av.y + ad.y; t = t > 0.f ? t : 0.2f * t; float aa1 = __expf(t - m1) * rd1;
      t = av.z + ad.z; t = t > 0.f ? t : 0.2f * t; float aa2 = __expf(t - m2) * rd2;
      t = av.w + ad.w; t = t > 0.f ? t : 0.2f * t; float aa3 = __expf(t - m3) * rd3;
      const u16* xr = xb + (size_t)s * 512;
      u32 v0 = *(const u32*)(xr);
      u32 v1 = *(const u32*)(xr + 128);
      u32 v2 = *(const u32*)(xr + 256);
      u32 v3 = *(const u32*)(xr + 384);
      o0 += aa0 * bf_lo(v0); o1 += aa0 * bf_hi(v0);
      o2 += aa1 * bf_lo(v1); o3 += aa1 * bf_hi(v1);
      o4 += aa2 * bf_lo(v2); o5 += aa2 * bf_hi(v2);
      o6 += aa3 * bf_lo(v3); o7 += aa3 * bf_hi(v3);
    }
  }
  // bias + relu + store (4 heads)
  float b0 = bf2f(canon[OFF_B1 + lane * 2]),       b1 = bf2f(canon[OFF_B1 + lane * 2 + 1]);
  float b2 = bf2f(canon[OFF_B1 + 128 + lane * 2]), b3 = bf2f(canon[OFF_B1 + 128 + lane * 2 + 1]);
  float b4 = bf2f(canon[OFF_B1 + 256 + lane * 2]), b5 = bf2f(canon[OFF_B1 + 256 + lane * 2 + 1]);
  float b6 = bf2f(canon[OFF_B1 + 384 + lane * 2]), b7 = bf2f(canon[OFF_B1 + 384 + lane * 2 + 1]);
  o0 += b0; o1 += b1; o2 += b2; o3 += b3; o4 += b4; o5 += b5; o6 += b6; o7 += b7;
  o0 = o0 > 0.f ? o0 : 0.f; o1 = o1 > 0.f ? o1 : 0.f;
  o2 = o2 > 0.f ? o2 : 0.f; o3 = o3 > 0.f ? o3 : 0.f;
  o4 = o4 > 0.f ? o4 : 0.f; o5 = o5 > 0.f ? o5 : 0.f;
  o6 = o6 > 0.f ? o6 : 0.f; o7 = o7 > 0.f ? o7 : 0.f;
  u16* hb = h1 + (size_t)n * 512 + lane * 2;
  *(u32*)(hb)       = cvtpk_bf16(o0, o1);
  *(u32*)(hb + 128) = cvtpk_bf16(o2, o3);
  *(u32*)(hb + 256) = cvtpk_bf16(o4, o5);
  *(u32*)(hb + 384) = cvtpk_bf16(o6, o7);
}

// GAT layer-2 aggregation + FUSED FC: wave holds full h2 row (lane = 2 feats),
// 10-class dot via shuffle reduce, direct output store.
__global__ __launch_bounds__(256) void k_agg2(
    const u16* __restrict__ xh2, const float* __restrict__ als2, const float* __restrict__ ald2,
    const int* __restrict__ offs, const int* __restrict__ csr,
    const u16* __restrict__ canon, void* __restrict__ out, const int* __restrict__ flag)
{
  const int lane = threadIdx.x & 63;
  const int n = blockIdx.x * 4 + (threadIdx.x >> 6);
  int off0 = offs[n], off1 = offs[n + 1];
  off0 = clampi(off0, 0, ETOT);
  off1 = clampi(off1, off0, ETOT);
  const float adn = ald2[n];
  const int deg = off1 - off0;

  float o0 = 0.f, o1 = 0.f;
  if (deg <= 64) {
    int s = 0;
    float e = -1e30f;
    if (lane < deg) {
      s = clampi(csr[off0 + lane], 0, NSEQ - 1);
      float t = als2[s] + adn;
      e = t > 0.f ? t : 0.2f * t;
    }
    float mx = e;
#pragma unroll
    for (int off = 32; off >= 1; off >>= 1) mx = fmaxf(mx, __shfl_xor(mx, off, 64));
    float ex = (lane < deg) ? __expf(e - mx) : 0.f;
    float sm = ex;
#pragma unroll
    for (int off = 32; off >= 1; off >>= 1) sm += __shfl_xor(sm, off, 64);
    const float a = ex * fast_rcp(sm + 1e-16f);
    const int sofs = s * 128;
#pragma unroll 4
    for (int j = 0; j < deg; ++j) {
      int so = __builtin_amdgcn_readlane(sofs, j);
      float aa = __int_as_float(__builtin_amdgcn_readlane(__float_as_int(a), j));
      u32 xv = *(const u32*)(xh2 + so + lane * 2);
      o0 += aa * bf_lo(xv);
      o1 += aa * bf_hi(xv);
    }
  } else {
    float mx = -1e30f;
    for (int k = off0 + lane; k < off1; k += 64) {
      float e = als2[clampi(csr[k], 0, NSEQ - 1)] + adn;
      e = e > 0.f ? e : 0.2f * e;
      mx = fmaxf(mx, e);
    }
#pragma unroll
    for (int off = 32; off >= 1; off >>= 1) mx = fmaxf(mx, __shfl_xor(mx, off, 64));
    float sm = 0.f;
    for (int k = off0 + lane; k < off1; k += 64) {
      float e = als2[clampi(csr[k], 0, NSEQ - 1)] + adn;
      e = e > 0.f ? e : 0.2f * e;
      sm += __expf(e - mx);
    }
#pragma unroll
    for (int off = 32; off >= 1; off >>= 1) sm += __shfl_xor(sm, off, 64);
    float rd = fast_rcp(sm + 1e-16f);
#pragma unroll 4
    for (int k = off0; k < off1; ++k) {
      int s = clampi(csr[k], 0, NSEQ - 1);
      float e = als2[s] + adn;
      e = e > 0.f ? e : 0.2f * e;
      float a = __expf(e - mx) * rd;
      u32 xv = *(const u32*)(xh2 + (size_t)s * 128 + lane * 2);
      o0 += a * bf_lo(xv);
      o1 += a * bf_hi(xv);
    }
  }
  o0 += bf2f(canon[OFF_B2 + lane * 2]);     o0 = o0 > 0.f ? o0 : 0.f;
  o1 += bf2f(canon[OFF_B2 + lane * 2 + 1]); o1 = o1 > 0.f ? o1 : 0.f;

  // fused FC: h2 row lives in (o0,o1) across the wave
  float res[10];
#pragma unroll
  for (int cls = 0; cls < 10; ++cls) {
    float p = o0 * bf2f(canon[OFF_WFC + cls * 128 + lane * 2]) +
              o1 * bf2f(canon[OFF_WFC + cls * 128 + lane * 2 + 1]);
#pragma unroll
    for (int off = 32; off >= 1; off >>= 1) p += __shfl_xor(p, off, 64);
    float v = p + bf2f(canon[OFF_BFC + cls]);
    res[cls] = (fabsf(v) < 1e30f) ? v : 0.f;
  }
  if (flag[0]) {
    if (lane < 5) {
      u32 pk = (u32)f2bf(res[lane * 2]) | ((u32)f2bf(res[lane * 2 + 1]) << 16);
      ((u32*)out)[(size_t)n * 5 + lane] = pk;
    }
  } else {
    if (lane < 10) ((float*)out)[(size_t)n * 10 + lane] = res[lane];
  }
}

__global__ void k_hist_all(const int* __restrict__ ei, const int* __restrict__ lengths,
                           int* __restrict__ deg, int* __restrict__ lcnt) {
  int i = blockIdx.x * 256 + threadIdx.x;
  if (i < ETOT) {
    int d = (i < EDG) ? ei[EDG + i] : (i - EDG);
    d = clampi(d, 0, NSEQ - 1);
    atomicAdd(&deg[d], 1);
  }
  if (i < NSEQ) atomicAdd(&lcnt[clampi(lengths[i], 1, TT) - 1], 1);
}

// single-block exclusive scan over deg (+ tiny serial length-scan by thread 0)
__global__ __launch_bounds__(1024) void k_scan(const int* __restrict__ deg,
                                               int* __restrict__ offs, int* __restrict__ cur,
                                               const int* __restrict__ lcnt,
                                               int* __restrict__ lcur) {
  __shared__ int wsum[16];
  const int tid = threadIdx.x;
  if (tid == 0) {
    int run = 0;
    for (int i = 0; i < TT; ++i) { lcur[i] = run; run += lcnt[i]; }
  }
  const int lane = tid & 63, wv = tid >> 6;
  const int CHUNK = 20;
  int base = tid * CHUNK;
  int loc[20];
  int s = 0;
#pragma unroll
  for (int i = 0; i < CHUNK; ++i) {
    int idx = base + i;
    int v = (idx < NSEQ) ? deg[idx] : 0;
    loc[i] = s;
    s += v;
  }
  int inc = s;
#pragma unroll
  for (int off = 1; off < 64; off <<= 1) {
    int t2 = __shfl_up(inc, off, 64);
    if (lane >= off) inc += t2;
  }
  if (lane == 63) wsum[wv] = inc;
  __syncthreads();
  int wbase = 0;
  for (int i = 0; i < wv; ++i) wbase += wsum[i];
  int tbase = wbase + inc - s;
#pragma unroll
  for (int i = 0; i < CHUNK; ++i) {
    int idx = base + i;
    if (idx < NSEQ) {
      int st = tbase + loc[i];
      offs[idx] = st;
      cur[idx] = st;
    }
  }
  if (tid == 0) offs[NSEQ] = ETOT;
}

__global__ void k_scatter_all(const int* __restrict__ ei, const int* __restrict__ lengths,
                              int* __restrict__ cur, int* __restrict__ csr,
                              int* __restrict__ lcur, int* __restrict__ lperm) {
  int i = blockIdx.x * 256 + threadIdx.x;
  if (i < ETOT) {
    int s, d;
    if (i < EDG) { s = ei[i]; d = ei[EDG + i]; }
    else { s = i - EDG; d = s; }
    d = clampi(d, 0, NSEQ - 1);
    int pos = atomicAdd(&cur[d], 1);
    pos = clampi(pos, 0, ETOT - 1);
    csr[pos] = s;
  }
  if (i < NSEQ) {
    int b = clampi(lengths[i], 1, TT) - 1;
    int pos = atomicAdd(&lcur[b], 1);
    lperm[clampi(pos, 0, NSEQ - 1)] = i;
  }
}

extern "C" void kernel_launch(void* const* d_in, const int* in_sizes, int n_in,
                              void* d_out, int out_size, void* d_ws, size_t ws_size,
                              hipStream_t stream) {
  (void)in_sizes; (void)n_in;
  const void* x     = d_in[0];
  const int* lengths= (const int*)d_in[1];
  const int* ei     = (const int*)d_in[2];

  const size_t NEED = 45769344u;
  if (ws_size < NEED) {
    k_fill0<<<(out_size + 255) / 256, 256, 0, stream>>>((u16*)d_out, out_size);
    return;
  }

  char* w = (char*)d_ws;
  size_t o = 0;
  auto alloc = [&](size_t b) { char* p = w + o; o += (b + 255) & ~(size_t)255; return p; };
  int*  flag = (int*)  alloc(256);
  u16*  canon= (u16*)  alloc(1048576);
  int*  deg  = (int*)  alloc((size_t)NSEQ * 4);
  int*  offs = (int*)  alloc((size_t)(NSEQ + 1) * 4);
  int*  cur  = (int*)  alloc((size_t)NSEQ * 4);
  int*  csr  = (int*)  alloc((size_t)ETOT * 4);
  float* als1= (float*)alloc((size_t)NSEQ * 4 * 4);
  float* ald1= (float*)alloc((size_t)NSEQ * 4 * 4);
  char* regB = alloc((size_t)NSEQ * 512 * 2);            // xh1 / later xh2,als2,ald2
  u16*  xh1  = (u16*)regB;
  u16*  xh2  = (u16*)regB;
  float* als2= (float*)(regB + (size_t)NSEQ * 128 * 2 + (size_t)NSEQ * 128 * 4);
  float* ald2= als2 + NSEQ;
  char* regA = alloc((size_t)NSEQ * 256 * 2);            // hcat / later h1 (w/ ext)
  u16*  hcat = (u16*)regA;
  u16*  h1   = (u16*)regA;
  alloc((size_t)NSEQ * 256 * 2);                         // h1 extension

  // length-sort scratch lives in regB (dead until k_gemm #1)
  int* lperm = (int*)regB;                       // 80000 B
  int* lcnt  = (int*)(regB + 80128);             // 32 ints
  int* lcur  = (int*)(regB + 80256);             // 32 ints

  // fused: zero deg/lcnt + dtype detect
  k_detect_zero<<<(NSEQ + 255) / 256, 256, 0, stream>>>((const u32*)x, flag, deg, lcnt);

  CvtArgs ca;
  const int srcIdx[16] = {3, 4, 5, 6, 7, 8, 9, 13, 10, 11, 12, 14, 15, 16, 17, 18};
  const int offv[16]   = {OFF_WIHF, OFF_WHHF, OFF_BF, OFF_WIHB, OFF_WHHB, OFF_BB,
                          OFF_W1, OFF_W2, OFF_A1S, OFF_A1D, OFF_B1,
                          OFF_A2S, OFF_A2D, OFF_B2, OFF_WFC, OFF_BFC};
  const int cntv[16]   = {65536, 65536, 512, 65536, 65536, 512,
                          131072, 65536, 512, 512, 512, 128, 128, 128, 1280, 10};
  const int wtv[16]    = {1, 1, 2, 1, 1, 2, 0, 0, 0, 0, 0, 0, 0, 0, 0, 0};
  for (int i = 0; i < 16; ++i) {
    ca.src[i] = d_in[srcIdx[i]]; ca.off[i] = offv[i]; ca.cnt[i] = cntv[i]; ca.wt[i] = wtv[i];
  }
  k_cvt<1><<<256, 256, 0, stream>>>(ca, canon, flag);
  k_cvt<0><<<256, 256, 0, stream>>>(ca, canon, flag);

  // setup: hist(deg+len) -> scan(offs/cur + lcur) -> scatter(csr + lperm)
  k_hist_all<<<(ETOT + 255) / 256, 256, 0, stream>>>(ei, lengths, deg, lcnt);
  k_scan<<<1, 1024, 0, stream>>>(deg, offs, cur, lcnt, lcur);
  k_scatter_all<<<(ETOT + 255) / 256, 256, 0, stream>>>(ei, lengths, cur, csr, lcur, lperm);

  k_lstm<1><<<dim3(157, 2), 512, 0, stream>>>(x, lengths, lperm, canon, hcat, flag);
  k_lstm<0><<<dim3(157, 2), 512, 0, stream>>>(x, lengths, lperm, canon, hcat, flag);

  k_gemm<<<dim3(157, 4), 256, 0, stream>>>(hcat, canon + OFF_W1, xh1, NSEQ, 512, 256,
                                           canon + OFF_A1S, canon + OFF_A1D, als1, ald1, 4);
  k_agg1<<<5000, 256, 0, stream>>>(xh1, als1, ald1, offs, csr, canon, h1);

  k_gemm<<<dim3(157, 1), 256, 0, stream>>>(h1, canon + OFF_W2, xh2, NSEQ, 128, 512,
                                           canon + OFF_A2S, canon + OFF_A2D, als2, ald2, 1);
  k_agg2<<<5000, 256, 0, stream>>>(xh2, als2, ald2, offs, csr, canon, d_out, flag);
}

// Round 5
// 748.133 us; speedup vs baseline: 1.3751x; 1.0707x over previous
//
#include <hip/hip_runtime.h>

#define NSEQ 20000
#define TT 20
#define FD 128
#define EDG 640000
#define ETOT (EDG + NSEQ)

typedef short bf16x8 __attribute__((ext_vector_type(8)));
typedef float f32x4 __attribute__((ext_vector_type(4)));
typedef unsigned short u16;
typedef unsigned int u32;

__device__ __forceinline__ float bf2f(u16 h) {
  union { u32 u; float f; } v; v.u = ((u32)h) << 16; return v.f;
}
__device__ __forceinline__ float bf_lo(u32 w) {
  union { u32 u; float f; } v; v.u = w << 16; return v.f;
}
__device__ __forceinline__ float bf_hi(u32 w) {
  union { u32 u; float f; } v; v.u = w & 0xffff0000u; return v.f;
}
__device__ __forceinline__ u16 f2bf(float f) {
  union { float f; u32 u; } v; v.f = f;
  u32 u = v.u;
  return (u16)((u + 0x7fffu + ((u >> 16) & 1u)) >> 16);
}
// v_rcp_f32: ~1ulp approx reciprocal, 1 instr instead of full-precision div (~9 instr)
__device__ __forceinline__ float fast_rcp(float x) {
  float r; asm("v_rcp_f32 %0, %1" : "=v"(r) : "v"(x)); return r;
}
// v_exp_f32: 2^x, single trans-pipe op (log2e pre-folded into weights)
__device__ __forceinline__ float fast_ex2(float x) {
  float r; asm("v_exp_f32 %0, %1" : "=v"(r) : "v"(x)); return r;
}
// packed fp32->bf16 (RNE), 2 elems/instr; lo = first arg
__device__ __forceinline__ u32 cvtpk_bf16(float a, float b) {
  u32 r; asm("v_cvt_pk_bf16_f32 %0, %1, %2" : "=v"(r) : "v"(a), "v"(b)); return r;
}
__device__ __forceinline__ int clampi(int v, int lo, int hi) {
  return v < lo ? lo : (v > hi ? hi : v);
}

// generic loaders over raw input (BF=1: bf16, BF=0: fp32)
template<int BF>
__device__ __forceinline__ bf16x8 ld8(const void* p, size_t i) {
  if (BF) return *(const bf16x8*)((const u16*)p + i);
  f32x4 a = *(const f32x4*)((const float*)p + i);
  f32x4 b = *(const f32x4*)((const float*)p + i + 4);
  union { u32 w[4]; bf16x8 v; } u;
  u.w[0] = cvtpk_bf16(a[0], a[1]);
  u.w[1] = cvtpk_bf16(a[2], a[3]);
  u.w[2] = cvtpk_bf16(b[0], b[1]);
  u.w[3] = cvtpk_bf16(b[2], b[3]);
  return u.v;
}

// canonical-weights element offsets (u16 units) inside the canon block
#define OFF_WIHF 0
#define OFF_WHHF 65536
#define OFF_BF   131072
#define OFF_WIHB 131584
#define OFF_WHHB 197120
#define OFF_BB   262656
#define OFF_W1   263168
#define OFF_W2   394240
#define OFF_A1S  459776
#define OFF_A1D  460288
#define OFF_B1   460800
#define OFF_A2S  461312
#define OFF_A2D  461440
#define OFF_B2   461568
#define OFF_WFC  461696
#define OFF_BFC  462976

// fused setup stage A: zero deg/lcnt + dtype detect (block 0, wave 0)
__global__ void k_detect_zero(const u32* __restrict__ xw, int* __restrict__ flag,
                              int* __restrict__ deg, int* __restrict__ lcnt) {
  int i = blockIdx.x * 256 + threadIdx.x;
  if (i < NSEQ) deg[i] = 0;
  if (i < 64) lcnt[i] = 0;
  if (blockIdx.x == 0 && threadIdx.x < 64) {
    u16 lo = (u16)(xw[threadIdx.x] & 0xffffu);
    int e = (lo >> 7) & 0xff;
    unsigned long long m = __ballot(e >= 100 && e <= 140);
    if (threadIdx.x == 0) flag[0] = (__popcll(m) >= 32) ? 1 : 0;
  }
}

struct CvtArgs {
  const void* src[16];
  int off[16];
  int cnt[16];
  int wt[16];   // 0: plain, 1: LSTM W (gate=(i>>14)&3), 2: LSTM bias (gate=(i>>7)&3)
};

// LSTM weights pre-scaled by -log2e (gates i,f,o) / +2*log2e (gate g) so the
// nonlinearity uses bare v_exp_f32 (2^x) with no feeding v_mul.
template<int BF>
__global__ void k_cvt(CvtArgs a, u16* __restrict__ canon, const int* __restrict__ flag) {
  if (flag[0] != BF) return;
  int idx = blockIdx.x * 256 + threadIdx.x;
  int stride = gridDim.x * 256;
#pragma unroll 1
  for (int s = 0; s < 16; ++s) {
    const void* sp = a.src[s];
    int n = a.cnt[s], off = a.off[s], wt = a.wt[s];
    for (int i = idx; i < n; i += stride) {
      float v = BF ? bf2f(((const u16*)sp)[i]) : ((const float*)sp)[i];
      if (wt) {
        int gate = (wt == 1) ? ((i >> 14) & 3) : ((i >> 7) & 3);
        v *= (gate == 2) ? 2.885390082f : -1.442695041f;
      }
      canon[off + i] = f2bf(v);
    }
  }
}

__global__ void k_fill0(u16* __restrict__ out, int n) {
  int i = blockIdx.x * 256 + threadIdx.x;
  if (i < n) out[i] = 0;
}

// ---------------------------------------------------------------------------
// Fused BiLSTM. Blocks take 64 length-sorted seqs; dispatch order is
// (dir0-longest, dir1-longest, dir0-next, ...) -- dir = blockIdx.x (fastest
// moving) so both directions' long blocks start in round 1 (greedy LPT).
// One barrier per step via double-buffered Ax/Ah; x(t+1) prefetch issued
// before the MFMA m-loop. SWAPPED-OPERAND MFMA: D[i=gatecol][j=seq]. Gate
// pre-activations arrive pre-scaled (log2e folded): 7 trans ops/cell.
// ---------------------------------------------------------------------------
template<int BF>
__global__ __launch_bounds__(512, 2) void k_lstm(
    const void* __restrict__ x, const int* __restrict__ lengths,
    const int* __restrict__ lperm,
    const u16* __restrict__ canon, u16* __restrict__ hcat,
    const int* __restrict__ flag)
{
  if (flag[0] != BF) return;
  __shared__ u16 Ax[2][64 * 128];
  __shared__ u16 Ah[2][64 * 128];
  __shared__ int lenS[64];
  __shared__ int seqS[64];

  const int tid = threadIdx.x;
  const int wv = tid >> 6;
  const int lane = tid & 63;
  const int q = lane >> 4;
  const int cc = lane & 15;
  const int dir = blockIdx.x;
  const int b0 = (gridDim.y - 1 - blockIdx.y) * 64;   // longest-first

  const u16* Wi = canon + (dir ? OFF_WIHB : OFF_WIHF);
  const u16* Wh = canon + (dir ? OFF_WHHB : OFF_WHHF);
  const u16* bb = canon + (dir ? OFF_BB : OFF_BF);

  // Weight fragments (A-operand): lane&15 = gate col, k = q*8+j.
  bf16x8 wih[4][4], whh[4][4];
  uint2 bvp[4];  // packed bf16 bias for cols wv*16+q*4 .. +3, per gate
#pragma unroll
  for (int g = 0; g < 4; ++g) {
    int row = g * 128 + wv * 16 + cc;
#pragma unroll
    for (int kt = 0; kt < 4; ++kt) {
      wih[g][kt] = *(const bf16x8*)(Wi + row * 128 + kt * 32 + q * 8);
      whh[g][kt] = *(const bf16x8*)(Wh + row * 128 + kt * 32 + q * 8);
    }
    bvp[g] = *(const uint2*)(bb + g * 128 + wv * 16 + q * 4);
  }

  if (tid < 64) {
    int s = lperm[clampi(b0 + tid, 0, NSEQ - 1)];
    s = clampi(s, 0, NSEQ - 1);
    seqS[tid] = s;
    lenS[tid] = clampi(lengths[s], 1, TT);
  }
  {
    f32x4 zz = {0.f, 0.f, 0.f, 0.f};
    f32x4* p = (f32x4*)Ah[0];
    for (int i = tid; i < 1024; i += 512) p[i] = zz;   // h0 = 0
  }
  __syncthreads();

  // sorted slice (clamped dups at the high end) -> block max = last entry
  const int tmax = lenS[63];

  // per-lane seq lengths (seq = m*16+cc; uniform over q,r)
  int lenq[4];
#pragma unroll
  for (int m = 0; m < 4; ++m) lenq[m] = lenS[m * 16 + cc];

  const int lrow = tid >> 3;
  const int lj = tid & 7;
  const int sL = seqS[lrow];
  const int lenL = lenS[lrow];
  const size_t xbase = (size_t)sL * (TT * FD);
  const int ax0 = lrow * 128 + ((lj ^ (lrow & 15)) * 8);
  const int ax1 = lrow * 128 + (((lj + 8) ^ (lrow & 15)) * 8);

  // hoisted XOR-swizzle offsets (constant over t)
  int rofs[4];
#pragma unroll
  for (int kt = 0; kt < 4; ++kt) rofs[kt] = cc * 128 + (((4 * kt + q) ^ cc) * 8);
  const int awbase = cc * 128 + (((wv * 2 + (q >> 1)) ^ cc) * 8) + (q & 1) * 4;

  {  // stage x(0) into Ax[0]
    int t0 = dir ? (lenL - 1) : 0;
    bf16x8 d0 = ld8<BF>(x, xbase + t0 * FD + lj * 8);
    bf16x8 d1 = ld8<BF>(x, xbase + t0 * FD + (lj + 8) * 8);
    *(bf16x8*)&Ax[0][ax0] = d0;
    *(bf16x8*)&Ax[0][ax1] = d1;
  }
  float c[4][4] = {};
  int cb = 0;
  __syncthreads();

#pragma unroll 1
  for (int t = 0; t < tmax; ++t) {
    const u16* Axr = Ax[cb];
    u16* Axw = Ax[cb ^ 1];
    const u16* Ahr = Ah[cb];
    u16* Ahw = Ah[cb ^ 1];

    // issue x(t+1) prefetch FIRST: its latency hides behind the MFMA m-loop
    bf16x8 d0 = {}, d1 = {};
    const bool more = (t + 1 < tmax);
    if (more) {
      int tn = t + 1;
      int tt2 = dir ? (lenL - 1 - tn) : tn;
      if (tt2 < 0) tt2 = 0;
      d0 = ld8<BF>(x, xbase + tt2 * FD + lj * 8);
      d1 = ld8<BF>(x, xbase + tt2 * FD + (lj + 8) * 8);
    }

#pragma unroll
    for (int m = 0; m < 4; ++m) {
      const int mb = m * 2048;
      f32x4 acc[4];
#pragma unroll
      for (int g = 0; g < 4; ++g) {
        f32x4 vi = {bf_lo(bvp[g].x), bf_hi(bvp[g].x), bf_lo(bvp[g].y), bf_hi(bvp[g].y)};
        acc[g] = vi;
      }
#pragma unroll
      for (int kt = 0; kt < 4; ++kt) {
        bf16x8 b = *(const bf16x8*)&Axr[mb + rofs[kt]];
#pragma unroll
        for (int g = 0; g < 4; ++g)
          acc[g] = __builtin_amdgcn_mfma_f32_16x16x32_bf16(wih[g][kt], b, acc[g], 0, 0, 0);
      }
#pragma unroll
      for (int kt = 0; kt < 4; ++kt) {
        bf16x8 b = *(const bf16x8*)&Ahr[mb + rofs[kt]];
#pragma unroll
        for (int g = 0; g < 4; ++g)
          acc[g] = __builtin_amdgcn_mfma_f32_16x16x32_bf16(whh[g][kt], b, acc[g], 0, 0, 0);
      }

      // fused-rcp nonlinearity; lane-uniform mask; packed b64 writeback
      uint2 hw;
      if (t < lenq[m]) {
        float hf[4];
#pragma unroll
        for (int r = 0; r < 4; ++r) {
          float Ei = fast_ex2(acc[0][r]);          // e^{-i}
          float Ef = fast_ex2(acc[1][r]);          // e^{-f}
          float G  = fast_ex2(acc[2][r]) + 1.0f;   // e^{2g}+1
          float Eo = fast_ex2(acc[3][r]);          // e^{-o}
          float A = 1.0f + Ef, B = 1.0f + Ei;
          float BG = B * G;
          float num = c[m][r] * BG + (A * G - 2.0f * A);
          float cn = num * fast_rcp(A * BG);
          c[m][r] = cn;
          float C2 = fast_ex2(cn * 2.885390082f) + 1.0f;
          hf[r] = (C2 - 2.0f) * fast_rcp((1.0f + Eo) * C2);
        }
        hw.x = cvtpk_bf16(hf[0], hf[1]);
        hw.y = cvtpk_bf16(hf[2], hf[3]);
      } else {
        hw = *(const uint2*)&Ahr[mb + awbase];   // carry old h
      }
      *(uint2*)&Ahw[mb + awbase] = hw;
    }

    // store prefetched x(t+1) into the OTHER Ax buffer (no reader this step)
    if (more) {
      *(bf16x8*)&Axw[ax0] = d0;
      *(bf16x8*)&Axw[ax1] = d1;
    }
    __syncthreads();   // single barrier per step
    cb ^= 1;
  }

  // epilogue: Ah[cb] holds last-valid h; write to hcat[seq, dir*128:+128]
  for (int i = tid; i < 1024; i += 512) {
    int row = i >> 4, ch = i & 15;
    if (b0 + row < NSEQ) {
      int seq = seqS[row];
      bf16x8 v = *(const bf16x8*)&Ah[cb][row * 128 + ((ch ^ (row & 15)) * 8)];
      *(bf16x8*)(hcat + (size_t)seq * 256 + dir * 128 + ch * 8) = v;
    }
  }
}

// ---------------------------------------------------------------------------
// Tiled bf16 GEMM: C[M,Nc] = A[M,K] * W[Nc,K]^T. Swapped-operand MFMA ->
// lane holds 4 consecutive cols -> dwordx2 C-stores. Fused attention-logit
// epilogue: als[row*stride+by] = sum_col C[row][col]*aS[col] (and aD).
// ---------------------------------------------------------------------------
__global__ __launch_bounds__(256) void k_gemm(
    const u16* __restrict__ A, const u16* __restrict__ W, u16* __restrict__ C,
    int M, int Nc, int K,
    const u16* __restrict__ aS, const u16* __restrict__ aD,
    float* __restrict__ als, float* __restrict__ ald, int alsStride)
{
  __shared__ u16 As[128 * 64];
  __shared__ u16 Bs[128 * 64];
  const int tid = threadIdx.x;
  const int wv = tid >> 6, lane = tid & 63, q = lane >> 4, cc = lane & 15;
  const int mblk = blockIdx.x * 128, nblk = blockIdx.y * 128;
  const int wm = (wv & 1) * 64, wn = (wv >> 1) * 64;

  f32x4 acc[4][4] = {};

  const int srow = tid >> 1;
  const int sc0 = (tid & 1) * 4;
  int arow_g = mblk + srow; if (arow_g > M - 1) arow_g = M - 1;
  const u16* aptr = A + (size_t)arow_g * K + sc0 * 8;
  const u16* bptr = W + (size_t)(nblk + srow) * K + sc0 * 8;

  for (int k0 = 0; k0 < K; k0 += 64) {
#pragma unroll
    for (int cch = 0; cch < 4; ++cch) {
      bf16x8 av = *(const bf16x8*)(aptr + k0 + cch * 8);
      bf16x8 bvv = *(const bf16x8*)(bptr + k0 + cch * 8);
      int ch = sc0 + cch;
      *(bf16x8*)&As[srow * 64 + ((ch ^ (srow & 7)) * 8)] = av;
      *(bf16x8*)&Bs[srow * 64 + ((ch ^ (srow & 7)) * 8)] = bvv;
    }
    __syncthreads();
#pragma unroll
    for (int kt = 0; kt < 2; ++kt) {
      bf16x8 af[4];
#pragma unroll
      for (int m = 0; m < 4; ++m) {
        int row = wm + m * 16 + cc;
        af[m] = *(const bf16x8*)&As[row * 64 + (((4 * kt + q) ^ (row & 7)) * 8)];
      }
#pragma unroll
      for (int n = 0; n < 4; ++n) {
        int rowb = wn + n * 16 + cc;
        bf16x8 bfr = *(const bf16x8*)&Bs[rowb * 64 + (((4 * kt + q) ^ (rowb & 7)) * 8)];
#pragma unroll
        for (int m = 0; m < 4; ++m)
          acc[m][n] = __builtin_amdgcn_mfma_f32_16x16x32_bf16(bfr, af[m], acc[m][n], 0, 0, 0);
      }
    }
    __syncthreads();
  }

  // C-store: lane = (seq row = wm+m*16+cc, cols wn+n*16+q*4..+3) -> dwordx2
  float pls[4] = {}, pld[4] = {};
#pragma unroll
  for (int n = 0; n < 4; ++n) {
    uint2 ws = *(const uint2*)(aS + nblk + wn + n * 16 + q * 4);
    uint2 wd = *(const uint2*)(aD + nblk + wn + n * 16 + q * 4);
    float s0 = bf_lo(ws.x), s1 = bf_hi(ws.x), s2 = bf_lo(ws.y), s3 = bf_hi(ws.y);
    float d0 = bf_lo(wd.x), d1 = bf_hi(wd.x), d2 = bf_lo(wd.y), d3 = bf_hi(wd.y);
#pragma unroll
    for (int m = 0; m < 4; ++m) {
      int row = mblk + wm + m * 16 + cc;
      uint2 st;
      st.x = cvtpk_bf16(acc[m][n][0], acc[m][n][1]);
      st.y = cvtpk_bf16(acc[m][n][2], acc[m][n][3]);
      if (row < M) *(uint2*)(C + (size_t)row * Nc + nblk + wn + n * 16 + q * 4) = st;
      pls[m] += acc[m][n][0] * s0 + acc[m][n][1] * s1 + acc[m][n][2] * s2 + acc[m][n][3] * s3;
      pld[m] += acc[m][n][0] * d0 + acc[m][n][1] * d1 + acc[m][n][2] * d2 + acc[m][n][3] * d3;
    }
  }

  // reduce over q (cols within wave), then across the two wn-halves via LDS
#pragma unroll
  for (int m = 0; m < 4; ++m) {
    pls[m] += __shfl_xor(pls[m], 16, 64);
    pls[m] += __shfl_xor(pls[m], 32, 64);
    pld[m] += __shfl_xor(pld[m], 16, 64);
    pld[m] += __shfl_xor(pld[m], 32, 64);
  }
  float* sred = (float*)As;   // 512 floats, As is free after last barrier
  if (lane < 16) {
#pragma unroll
    for (int m = 0; m < 4; ++m) {
      int idx = ((wv & 1) * 4 + m) * 32 + cc * 2 + (wv >> 1);
      sred[idx] = pls[m];
      sred[256 + idx] = pld[m];
    }
  }
  __syncthreads();
  if (wv < 2) {
    int m = lane >> 4, ccc = lane & 15;
    int row = mblk + wv * 64 + m * 16 + ccc;
    int idx = (wv * 4 + m) * 32 + ccc * 2;
    if (row < M) {
      als[(size_t)row * alsStride + blockIdx.y] = sred[idx] + sred[idx + 1];
      ald[(size_t)row * alsStride + blockIdx.y] = sred[256 + idx] + sred[256 + idx + 1];
    }
  }
}

// GAT layer-1 softmax + aggregation: one WAVE per node covering ALL 4 heads
// (4 independent gather loads/edge -> 4x memory ILP; als/ald/csr read once).
__global__ __launch_bounds__(256) void k_agg1(
    const u16* __restrict__ xh1, const float* __restrict__ als, const float* __restrict__ ald,
    const int* __restrict__ offs, const int* __restrict__ csr,
    const u16* __restrict__ canon, u16* __restrict__ h1)
{
  const int lane = threadIdx.x & 63;
  const int n = blockIdx.x * 4 + (threadIdx.x >> 6);
  int off0 = offs[n], off1 = offs[n + 1];
  off0 = clampi(off0, 0, ETOT);
  off1 = clampi(off1, off0, ETOT);
  const int deg = off1 - off0;
  const float4 ad = *(const float4*)(ald + (size_t)n * 4);
  const u16* xb = xh1 + lane * 2;

  float o0 = 0.f, o1 = 0.f, o2 = 0.f, o3 = 0.f, o4 = 0.f, o5 = 0.f, o6 = 0.f, o7 = 0.f;
  if (deg <= 64) {
    int s = 0;
    float e0 = -1e30f, e1 = -1e30f, e2 = -1e30f, e3 = -1e30f;
    if (lane < deg) {
      s = clampi(csr[off0 + lane], 0, NSEQ - 1);
      float4 av = *(const float4*)(als + (size_t)s * 4);
      float t;
      t = av.x + ad.x; e0 = t > 0.f ? t : 0.2f * t;
      t = av.y + ad.y; e1 = t > 0.f ? t : 0.2f * t;
      t = av.z + ad.z; e2 = t > 0.f ? t : 0.2f * t;
      t = av.w + ad.w; e3 = t > 0.f ? t : 0.2f * t;
    }
    float m0 = e0, m1 = e1, m2 = e2, m3 = e3;
#pragma unroll
    for (int off = 32; off >= 1; off >>= 1) {
      m0 = fmaxf(m0, __shfl_xor(m0, off, 64));
      m1 = fmaxf(m1, __shfl_xor(m1, off, 64));
      m2 = fmaxf(m2, __shfl_xor(m2, off, 64));
      m3 = fmaxf(m3, __shfl_xor(m3, off, 64));
    }
    float x0 = (lane < deg) ? __expf(e0 - m0) : 0.f;
    float x1 = (lane < deg) ? __expf(e1 - m1) : 0.f;
    float x2 = (lane < deg) ? __expf(e2 - m2) : 0.f;
    float x3 = (lane < deg) ? __expf(e3 - m3) : 0.f;
    float s0 = x0, s1 = x1, s2 = x2, s3 = x3;
#pragma unroll
    for (int off = 32; off >= 1; off >>= 1) {
      s0 += __shfl_xor(s0, off, 64);
      s1 += __shfl_xor(s1, off, 64);
      s2 += __shfl_xor(s2, off, 64);
      s3 += __shfl_xor(s3, off, 64);
    }
    float a0 = x0 * fast_rcp(s0 + 1e-16f);
    float a1 = x1 * fast_rcp(s1 + 1e-16f);
    float a2 = x2 * fast_rcp(s2 + 1e-16f);
    float a3 = x3 * fast_rcp(s3 + 1e-16f);
    const int sofs = s * 512;
#pragma unroll 4
    for (int j = 0; j < deg; ++j) {
      int so = __builtin_amdgcn_readlane(sofs, j);
      float aa0 = __int_as_float(__builtin_amdgcn_readlane(__float_as_int(a0), j));
      float aa1 = __int_as_float(__builtin_amdgcn_readlane(__float_as_int(a1), j));
      float aa2 = __int_as_float(__builtin_amdgcn_readlane(__float_as_int(a2), j));
      float aa3 = __int_as_float(__builtin_amdgcn_readlane(__float_as_int(a3), j));
      u32 v0 = *(const u32*)(xb + so);
      u32 v1 = *(const u32*)(xb + so + 128);
      u32 v2 = *(const u32*)(xb + so + 256);
      u32 v3 = *(const u32*)(xb + so + 384);
      o0 += aa0 * bf_lo(v0); o1 += aa0 * bf_hi(v0);
      o2 += aa1 * bf_lo(v1); o3 += aa1 * bf_hi(v1);
      o4 += aa2 * bf_lo(v2); o5 += aa2 * bf_hi(v2);
      o6 += aa3 * bf_lo(v3); o7 += aa3 * bf_hi(v3);
    }
  } else {
    float m0 = -1e30f, m1 = -1e30f, m2 = -1e30f, m3 = -1e30f;
    for (int k = off0 + lane; k < off1; k += 64) {
      int s = clampi(csr[k], 0, NSEQ - 1);
      float4 av = *(const float4*)(als + (size_t)s * 4);
      float t;
      t = av.x + ad.x; t = t > 0.f ? t : 0.2f * t; m0 = fmaxf(m0, t);
      t = av.y + ad.y; t = t > 0.f ? t : 0.2f * t; m1 = fmaxf(m1, t);
      t = av.z + ad.z; t = t > 0.f ? t : 0.2f * t; m2 = fmaxf(m2, t);
      t = av.w + ad.w; t = t > 0.f ? t : 0.2f * t; m3 = fmaxf(m3, t);
    }
#pragma unroll
    for (int off = 32; off >= 1; off >>= 1) {
      m0 = fmaxf(m0, __shfl_xor(m0, off, 64));
      m1 = fmaxf(m1, __shfl_xor(m1, off, 64));
      m2 = fmaxf(m2, __shfl_xor(m2, off, 64));
      m3 = fmaxf(m3, __shfl_xor(m3, off, 64));
    }
    float s0 = 0.f, s1 = 0.f, s2 = 0.f, s3 = 0.f;
    for (int k = off0 + lane; k < off1; k += 64) {
      int s = clampi(csr[k], 0, NSEQ - 1);
      float4 av = *(const float4*)(als + (size_t)s * 4);
      float t;
      t = av.x + ad.x; t = t > 0.f ? t : 0.2f * t; s0 += __expf(t - m0);
      t = av.y + ad.y; t = t > 0.f ? t : 0.2f * t; s1 += __expf(t - m1);
      t = av.z + ad.z; t = t > 0.f ? t : 0.2f * t; s2 += __expf(t - m2);
      t = av.w + ad.w; t = t > 0.f ? t : 0.2f * t; s3 += __expf(t - m3);
    }
#pragma unroll
    for (int off = 32; off >= 1; off >>= 1) {
      s0 += __shfl_xor(s0, off, 64);
      s1 += __shfl_xor(s1, off, 64);
      s2 += __shfl_xor(s2, off, 64);
      s3 += __shfl_xor(s3, off, 64);
    }
    float rd0 = fast_rcp(s0 + 1e-16f), rd1 = fast_rcp(s1 + 1e-16f);
    float rd2 = fast_rcp(s2 + 1e-16f), rd3 = fast_rcp(s3 + 1e-16f);
    for (int k = off0; k < off1; ++k) {
      int s = clampi(csr[k], 0, NSEQ - 1);
      float4 av = *(const float4*)(als + (size_t)s * 4);
      float t;
      t = av.x + ad.x; t = t > 0.f ? t : 0.2f * t; float aa0 = __expf(t - m0) * rd0;
      t = av.y + ad.y; t = t > 0.f ? t : 0.2f * t; float aa1 = __expf(t - m1) * rd1;
      t = av.z + ad.z; t = t > 0.f ? t : 0.2f * t; float aa2 = __expf(t - m2) * rd2;
      t = av.w + ad.w; t = t > 0.f ? t : 0.2f * t; float aa3 = __expf(t - m3) * rd3;
      const u16* xr = xb + (size_t)s * 512;
      u32 v0 = *(const u32*)(xr);
      u32 v1 = *(const u32*)(xr + 128);
      u32 v2 = *(const u32*)(xr + 256);
      u32 v3 = *(const u32*)(xr + 384);
      o0 += aa0 * bf_lo(v0); o1 += aa0 * bf_hi(v0);
      o2 += aa1 * bf_lo(v1); o3 += aa1 * bf_hi(v1);
      o4 += aa2 * bf_lo(v2); o5 += aa2 * bf_hi(v2);
      o6 += aa3 * bf_lo(v3); o7 += aa3 * bf_hi(v3);
    }
  }
  // bias + relu + store (4 heads)
  float b0 = bf2f(canon[OFF_B1 + lane * 2]),       b1 = bf2f(canon[OFF_B1 + lane * 2 + 1]);
  float b2 = bf2f(canon[OFF_B1 + 128 + lane * 2]), b3 = bf2f(canon[OFF_B1 + 128 + lane * 2 + 1]);
  float b4 = bf2f(canon[OFF_B1 + 256 + lane * 2]), b5 = bf2f(canon[OFF_B1 + 256 + lane * 2 + 1]);
  float b6 = bf2f(canon[OFF_B1 + 384 + lane * 2]), b7 = bf2f(canon[OFF_B1 + 384 + lane * 2 + 1]);
  o0 += b0; o1 += b1; o2 += b2; o3 += b3; o4 += b4; o5 += b5; o6 += b6; o7 += b7;
  o0 = o0 > 0.f ? o0 : 0.f; o1 = o1 > 0.f ? o1 : 0.f;
  o2 = o2 > 0.f ? o2 : 0.f; o3 = o3 > 0.f ? o3 : 0.f;
  o4 = o4 > 0.f ? o4 : 0.f; o5 = o5 > 0.f ? o5 : 0.f;
  o6 = o6 > 0.f ? o6 : 0.f; o7 = o7 > 0.f ? o7 : 0.f;
  u16* hb = h1 + (size_t)n * 512 + lane * 2;
  *(u32*)(hb)       = cvtpk_bf16(o0, o1);
  *(u32*)(hb + 128) = cvtpk_bf16(o2, o3);
  *(u32*)(hb + 256) = cvtpk_bf16(o4, o5);
  *(u32*)(hb + 384) = cvtpk_bf16(o6, o7);
}

// GAT layer-2 aggregation + FUSED FC: wave holds full h2 row (lane = 2 feats),
// 10-class dot via shuffle reduce, direct output store.
__global__ __launch_bounds__(256) void k_agg2(
    const u16* __restrict__ xh2, const float* __restrict__ als2, const float* __restrict__ ald2,
    const int* __restrict__ offs, const int* __restrict__ csr,
    const u16* __restrict__ canon, void* __restrict__ out, const int* __restrict__ flag)
{
  const int lane = threadIdx.x & 63;
  const int n = blockIdx.x * 4 + (threadIdx.x >> 6);
  int off0 = offs[n], off1 = offs[n + 1];
  off0 = clampi(off0, 0, ETOT);
  off1 = clampi(off1, off0, ETOT);
  const float adn = ald2[n];
  const int deg = off1 - off0;

  float o0 = 0.f, o1 = 0.f;
  if (deg <= 64) {
    int s = 0;
    float e = -1e30f;
    if (lane < deg) {
      s = clampi(csr[off0 + lane], 0, NSEQ - 1);
      float t = als2[s] + adn;
      e = t > 0.f ? t : 0.2f * t;
    }
    float mx = e;
#pragma unroll
    for (int off = 32; off >= 1; off >>= 1) mx = fmaxf(mx, __shfl_xor(mx, off, 64));
    float ex = (lane < deg) ? __expf(e - mx) : 0.f;
    float sm = ex;
#pragma unroll
    for (int off = 32; off >= 1; off >>= 1) sm += __shfl_xor(sm, off, 64);
    const float a = ex * fast_rcp(sm + 1e-16f);
    const int sofs = s * 128;
#pragma unroll 4
    for (int j = 0; j < deg; ++j) {
      int so = __builtin_amdgcn_readlane(sofs, j);
      float aa = __int_as_float(__builtin_amdgcn_readlane(__float_as_int(a), j));
      u32 xv = *(const u32*)(xh2 + so + lane * 2);
      o0 += aa * bf_lo(xv);
      o1 += aa * bf_hi(xv);
    }
  } else {
    float mx = -1e30f;
    for (int k = off0 + lane; k < off1; k += 64) {
      float e = als2[clampi(csr[k], 0, NSEQ - 1)] + adn;
      e = e > 0.f ? e : 0.2f * e;
      mx = fmaxf(mx, e);
    }
#pragma unroll
    for (int off = 32; off >= 1; off >>= 1) mx = fmaxf(mx, __shfl_xor(mx, off, 64));
    float sm = 0.f;
    for (int k = off0 + lane; k < off1; k += 64) {
      float e = als2[clampi(csr[k], 0, NSEQ - 1)] + adn;
      e = e > 0.f ? e : 0.2f * e;
      sm += __expf(e - mx);
    }
#pragma unroll
    for (int off = 32; off >= 1; off >>= 1) sm += __shfl_xor(sm, off, 64);
    float rd = fast_rcp(sm + 1e-16f);
#pragma unroll 4
    for (int k = off0; k < off1; ++k) {
      int s = clampi(csr[k], 0, NSEQ - 1);
      float e = als2[s] + adn;
      e = e > 0.f ? e : 0.2f * e;
      float a = __expf(e - mx) * rd;
      u32 xv = *(const u32*)(xh2 + (size_t)s * 128 + lane * 2);
      o0 += a * bf_lo(xv);
      o1 += a * bf_hi(xv);
    }
  }
  o0 += bf2f(canon[OFF_B2 + lane * 2]);     o0 = o0 > 0.f ? o0 : 0.f;
  o1 += bf2f(canon[OFF_B2 + lane * 2 + 1]); o1 = o1 > 0.f ? o1 : 0.f;

  // fused FC: h2 row lives in (o0,o1) across the wave
  float res[10];
#pragma unroll
  for (int cls = 0; cls < 10; ++cls) {
    float p = o0 * bf2f(canon[OFF_WFC + cls * 128 + lane * 2]) +
              o1 * bf2f(canon[OFF_WFC + cls * 128 + lane * 2 + 1]);
#pragma unroll
    for (int off = 32; off >= 1; off >>= 1) p += __shfl_xor(p, off, 64);
    float v = p + bf2f(canon[OFF_BFC + cls]);
    res[cls] = (fabsf(v) < 1e30f) ? v : 0.f;
  }
  if (flag[0]) {
    if (lane < 5) {
      u32 pk = (u32)f2bf(res[lane * 2]) | ((u32)f2bf(res[lane * 2 + 1]) << 16);
      ((u32*)out)[(size_t)n * 5 + lane] = pk;
    }
  } else {
    if (lane < 10) ((float*)out)[(size_t)n * 10 + lane] = res[lane];
  }
}

__global__ void k_hist_all(const int* __restrict__ ei, const int* __restrict__ lengths,
                           int* __restrict__ deg, int* __restrict__ lcnt) {
  int i = blockIdx.x * 256 + threadIdx.x;
  if (i < ETOT) {
    int d = (i < EDG) ? ei[EDG + i] : (i - EDG);
    d = clampi(d, 0, NSEQ - 1);
    atomicAdd(&deg[d], 1);
  }
  if (i < NSEQ) atomicAdd(&lcnt[clampi(lengths[i], 1, TT) - 1], 1);
}

// single-block exclusive scan over deg (+ tiny serial length-scan by thread 0)
__global__ __launch_bounds__(1024) void k_scan(const int* __restrict__ deg,
                                               int* __restrict__ offs, int* __restrict__ cur,
                                               const int* __restrict__ lcnt,
                                               int* __restrict__ lcur) {
  __shared__ int wsum[16];
  const int tid = threadIdx.x;
  if (tid == 0) {
    int run = 0;
    for (int i = 0; i < TT; ++i) { lcur[i] = run; run += lcnt[i]; }
  }
  const int lane = tid & 63, wv = tid >> 6;
  const int CHUNK = 20;
  int base = tid * CHUNK;
  int loc[20];
  int s = 0;
#pragma unroll
  for (int i = 0; i < CHUNK; ++i) {
    int idx = base + i;
    int v = (idx < NSEQ) ? deg[idx] : 0;
    loc[i] = s;
    s += v;
  }
  int inc = s;
#pragma unroll
  for (int off = 1; off < 64; off <<= 1) {
    int t2 = __shfl_up(inc, off, 64);
    if (lane >= off) inc += t2;
  }
  if (lane == 63) wsum[wv] = inc;
  __syncthreads();
  int wbase = 0;
  for (int i = 0; i < wv; ++i) wbase += wsum[i];
  int tbase = wbase + inc - s;
#pragma unroll
  for (int i = 0; i < CHUNK; ++i) {
    int idx = base + i;
    if (idx < NSEQ) {
      int st = tbase + loc[i];
      offs[idx] = st;
      cur[idx] = st;
    }
  }
  if (tid == 0) offs[NSEQ] = ETOT;
}

__global__ void k_scatter_all(const int* __restrict__ ei, const int* __restrict__ lengths,
                              int* __restrict__ cur, int* __restrict__ csr,
                              int* __restrict__ lcur, int* __restrict__ lperm) {
  int i = blockIdx.x * 256 + threadIdx.x;
  if (i < ETOT) {
    int s, d;
    if (i < EDG) { s = ei[i]; d = ei[EDG + i]; }
    else { s = i - EDG; d = s; }
    d = clampi(d, 0, NSEQ - 1);
    int pos = atomicAdd(&cur[d], 1);
    pos = clampi(pos, 0, ETOT - 1);
    csr[pos] = s;
  }
  if (i < NSEQ) {
    int b = clampi(lengths[i], 1, TT) - 1;
    int pos = atomicAdd(&lcur[b], 1);
    lperm[clampi(pos, 0, NSEQ - 1)] = i;
  }
}

extern "C" void kernel_launch(void* const* d_in, const int* in_sizes, int n_in,
                              void* d_out, int out_size, void* d_ws, size_t ws_size,
                              hipStream_t stream) {
  (void)in_sizes; (void)n_in;
  const void* x     = d_in[0];
  const int* lengths= (const int*)d_in[1];
  const int* ei     = (const int*)d_in[2];

  const size_t NEED = 45769344u;
  if (ws_size < NEED) {
    k_fill0<<<(out_size + 255) / 256, 256, 0, stream>>>((u16*)d_out, out_size);
    return;
  }

  char* w = (char*)d_ws;
  size_t o = 0;
  auto alloc = [&](size_t b) { char* p = w + o; o += (b + 255) & ~(size_t)255; return p; };
  int*  flag = (int*)  alloc(256);
  u16*  canon= (u16*)  alloc(1048576);
  int*  deg  = (int*)  alloc((size_t)NSEQ * 4);
  int*  offs = (int*)  alloc((size_t)(NSEQ + 1) * 4);
  int*  cur  = (int*)  alloc((size_t)NSEQ * 4);
  int*  csr  = (int*)  alloc((size_t)ETOT * 4);
  float* als1= (float*)alloc((size_t)NSEQ * 4 * 4);
  float* ald1= (float*)alloc((size_t)NSEQ * 4 * 4);
  char* regB = alloc((size_t)NSEQ * 512 * 2);            // xh1 / later xh2,als2,ald2
  u16*  xh1  = (u16*)regB;
  u16*  xh2  = (u16*)regB;
  float* als2= (float*)(regB + (size_t)NSEQ * 128 * 2 + (size_t)NSEQ * 128 * 4);
  float* ald2= als2 + NSEQ;
  char* regA = alloc((size_t)NSEQ * 256 * 2);            // hcat / later h1 (w/ ext)
  u16*  hcat = (u16*)regA;
  u16*  h1   = (u16*)regA;
  alloc((size_t)NSEQ * 256 * 2);                         // h1 extension

  // length-sort scratch lives in regB (dead until k_gemm #1)
  int* lperm = (int*)regB;                       // 80000 B
  int* lcnt  = (int*)(regB + 80128);             // 32 ints
  int* lcur  = (int*)(regB + 80256);             // 32 ints

  // fused: zero deg/lcnt + dtype detect
  k_detect_zero<<<(NSEQ + 255) / 256, 256, 0, stream>>>((const u32*)x, flag, deg, lcnt);

  CvtArgs ca;
  const int srcIdx[16] = {3, 4, 5, 6, 7, 8, 9, 13, 10, 11, 12, 14, 15, 16, 17, 18};
  const int offv[16]   = {OFF_WIHF, OFF_WHHF, OFF_BF, OFF_WIHB, OFF_WHHB, OFF_BB,
                          OFF_W1, OFF_W2, OFF_A1S, OFF_A1D, OFF_B1,
                          OFF_A2S, OFF_A2D, OFF_B2, OFF_WFC, OFF_BFC};
  const int cntv[16]   = {65536, 65536, 512, 65536, 65536, 512,
                          131072, 65536, 512, 512, 512, 128, 128, 128, 1280, 10};
  const int wtv[16]    = {1, 1, 2, 1, 1, 2, 0, 0, 0, 0, 0, 0, 0, 0, 0, 0};
  for (int i = 0; i < 16; ++i) {
    ca.src[i] = d_in[srcIdx[i]]; ca.off[i] = offv[i]; ca.cnt[i] = cntv[i]; ca.wt[i] = wtv[i];
  }
  k_cvt<1><<<256, 256, 0, stream>>>(ca, canon, flag);
  k_cvt<0><<<256, 256, 0, stream>>>(ca, canon, flag);

  // setup: hist(deg+len) -> scan(offs/cur + lcur) -> scatter(csr + lperm)
  k_hist_all<<<(ETOT + 255) / 256, 256, 0, stream>>>(ei, lengths, deg, lcnt);
  k_scan<<<1, 1024, 0, stream>>>(deg, offs, cur, lcnt, lcur);
  k_scatter_all<<<(ETOT + 255) / 256, 256, 0, stream>>>(ei, lengths, cur, csr, lcur, lperm);

  // dir = x (fastest-moving): both directions' longest blocks dispatch first
  k_lstm<1><<<dim3(2, 313), 512, 0, stream>>>(x, lengths, lperm, canon, hcat, flag);
  k_lstm<0><<<dim3(2, 313), 512, 0, stream>>>(x, lengths, lperm, canon, hcat, flag);

  k_gemm<<<dim3(157, 4), 256, 0, stream>>>(hcat, canon + OFF_W1, xh1, NSEQ, 512, 256,
                                           canon + OFF_A1S, canon + OFF_A1D, als1, ald1, 4);
  k_agg1<<<5000, 256, 0, stream>>>(xh1, als1, ald1, offs, csr, canon, h1);

  k_gemm<<<dim3(157, 1), 256, 0, stream>>>(h1, canon + OFF_W2, xh2, NSEQ, 128, 512,
                                           canon + OFF_A2S, canon + OFF_A2D, als2, ald2, 1);
  k_agg2<<<5000, 256, 0, stream>>>(xh2, als2, ald2, offs, csr, canon, d_out, flag);
}